// Round 3
// baseline (4608.184 us; speedup 1.0000x reference)
//
#include <hip/hip_runtime.h>
#include <cstdint>

#define B_   4
#define L_   1024
#define H_   256
#define NE_  64
#define P_   512
#define E_   65536
#define R_   4
#define DW_  100
#define DC_  20
#define DT_  20
#define DD_  20
#define REL_ 97
#define N_   256      // B*NE
#define D2_  512
#define DBI_ 276
#define DIN_ 140
#define G4_  1024     // 4*H

// workspace offsets in floats
#define OFF_EMB  0u
#define OFF_PRE  573440u
#define OFF_DOCS 8962048u
#define OFF_WHP  11059200u
#define OFF_ENT  11321344u
#define OFF_M    11452416u
#define OFF_AGG  11976704u
#define OFF_HS   12107776u
#define OFF_TS   12238848u
#define OFF_HD   12369920u
#define OFF_TD   12935168u
#define OFF_HPTP 13500416u
#define OFF_BL   14024704u
// f16 buffers overlaid on emb/pre/docs (dead after k_pool):
#define OFF_WB_F16   0u
#define OFF_HDB_F16  10174464u
#define OFF_TDB_F16  10469376u

typedef _Float16 h2v __attribute__((ext_vector_type(2)));
typedef _Float16 h8v __attribute__((ext_vector_type(8)));
typedef float f4v __attribute__((ext_vector_type(4)));
typedef unsigned int u4v __attribute__((ext_vector_type(4)));

union AFrag { h8v v; h2v h[4]; };
union TDreg { u4v u; h2v h[4]; };

__device__ __forceinline__ unsigned short f16bits(float x) {
    return __builtin_bit_cast(unsigned short, (_Float16)x);
}

// fast hw transcendentals: v_exp_f32 computes 2^x, v_rcp_f32 ~1ulp.
#if __has_builtin(__builtin_amdgcn_exp2f)
#define EXP2F __builtin_amdgcn_exp2f
#else
#define EXP2F exp2f
#endif
#if __has_builtin(__builtin_amdgcn_rcpf)
#define RCPF __builtin_amdgcn_rcpf
#else
#define RCPF(x) (1.0f / (x))
#endif

__device__ __forceinline__ float fast_sig(float x) {
    return RCPF(1.0f + EXP2F(x * -1.44269504f));
}
__device__ __forceinline__ float fast_tanh(float x) {
    return 1.0f - 2.0f * RCPF(EXP2F(x * 2.88539008f) + 1.0f);
}

__device__ __forceinline__ f4v MF(h8v a, u4v b, f4v c) {
    return __builtin_amdgcn_mfma_f32_16x16x32_f16(
        a, __builtin_bit_cast(h8v, b), c, 0, 0, 0);
}

// ---------------------------------------------------------------- embeddings
__global__ __launch_bounds__(192) void k_embed(
    const float* __restrict__ wt, const float* __restrict__ ct,
    const float* __restrict__ nt, const int* __restrict__ widx,
    const int* __restrict__ pidx, const int* __restrict__ nidx,
    float* __restrict__ emb) {
    int row = blockIdx.x;               // b*L + l
    int t = threadIdx.x;
    if (t >= DIN_) return;
    float v;
    if (t < DW_)            v = wt[(size_t)widx[row] * DW_ + t];
    else if (t < DW_ + DC_) v = ct[pidx[row] * DC_ + (t - DW_)];
    else                    v = nt[nidx[row] * DT_ + (t - DW_ - DC_)];
    emb[(size_t)row * DIN_ + t] = v;
}

// -------- pack Wh (both dirs) into MFMA B-fragment layout (f16 pairs)
// whp u32 index = (((dir*64 + n)*8 + kk)*64 + lane)*4 + m
// value: pack(f16(Wh[k0][col]), f16(Wh[k0+1][col]))
//   k0 = kk*32 + (lane>>4)*8 + 2m, col = n*16 + (lane&15)
// = per-lane B operand of v_mfma_f32_16x16x32_f16 for tile n, K-tile kk.
__global__ __launch_bounds__(256) void k_pack_wh(
    const float* __restrict__ whf, const float* __restrict__ whb,
    unsigned* __restrict__ whp) {
    unsigned gid = blockIdx.x * 256 + threadIdx.x;   // 2^18 total
    unsigned m    = gid & 3u;
    unsigned lane = (gid >> 2) & 63u;
    unsigned kk   = (gid >> 8) & 7u;
    unsigned n    = (gid >> 11) & 63u;
    unsigned dir  = gid >> 17;
    const float* src = dir ? whb : whf;
    unsigned k0  = kk * 32u + (lane >> 4) * 8u + 2u * m;
    unsigned col = n * 16u + (lane & 15u);
    unsigned lo = f16bits(src[(size_t)k0 * G4_ + col]);
    unsigned hi = f16bits(src[(size_t)(k0 + 1) * G4_ + col]);
    whp[gid] = (hi << 16) | lo;
}

// ----------------------------------------- pre-gates: emb @ Wi + b (both dirs)
__global__ __launch_bounds__(256) void k_pregates(
    const float* __restrict__ emb,
    const float* __restrict__ wif, const float* __restrict__ bf,
    const float* __restrict__ wib, const float* __restrict__ bb,
    float* __restrict__ pre) {
    int dir = blockIdx.y;
    const float* Wi   = dir ? wib : wif;
    const float* bias = dir ? bb : bf;
    int x8 = blockIdx.x * 8;            // 8 (b,l) rows per block
    __shared__ float se[8 * DIN_];
    for (int idx = threadIdx.x; idx < 8 * DIN_; idx += 256)
        se[idx] = emb[(size_t)(x8 + idx / DIN_) * DIN_ + idx % DIN_];
    __syncthreads();
    int t = threadIdx.x;
    float acc[8][4];
#pragma unroll
    for (int r = 0; r < 8; r++)
#pragma unroll
        for (int q = 0; q < 4; q++) acc[r][q] = bias[t + q * 256];
    for (int k = 0; k < DIN_; k++) {
        float w0 = Wi[k * G4_ + t];
        float w1 = Wi[k * G4_ + t + 256];
        float w2 = Wi[k * G4_ + t + 512];
        float w3 = Wi[k * G4_ + t + 768];
#pragma unroll
        for (int r = 0; r < 8; r++) {
            float e = se[r * DIN_ + k];
            acc[r][0] += e * w0; acc[r][1] += e * w1;
            acc[r][2] += e * w2; acc[r][3] += e * w3;
        }
    }
#pragma unroll
    for (int r = 0; r < 8; r++) {
        float* dst = pre + ((size_t)(dir * 4096 + x8 + r)) * G4_ + t;
        dst[0] = acc[r][0]; dst[256] = acc[r][1];
        dst[512] = acc[r][2]; dst[768] = acc[r][3];
    }
}

// --------------- BiLSTM v4: MFMA recurrence, 2 waves/SIMD for latency hiding.
// 8 blocks (dir x batch) x 512 threads = 8 waves: wave = (col-set s in 0..3,
// K-half g in 0..1). Set s owns tiles n = s+4j (j=0..15); wave covers
// kk in [4g,4g+4). Unit u = 16s+c+64jj uses tiles {jj, jj+4, jj+8, jj+12}
// (i,f,g,o). Tiles j=0..11 (i/f/g gates): K-half frags in VGPR (192 regs).
// Tiles j=12..15 (o gates): LDS (128 KiB) -> only 16 per-lane ds_read_b128
// per thread per step. h-frag reads are same-address broadcasts (cheap).
// K-halves combine via sgp LDS exchange (g1 publishes raw partials); g0
// q==0 lanes add pre, run exp2 activations, write h (f16) + docs.
__global__ __launch_bounds__(512, 2) void k_lstm(
    const float* __restrict__ pre, const unsigned* __restrict__ whb,
    float* __restrict__ docs) {
    int dir = blockIdx.x >> 2, b = blockIdx.x & 3;
    int tid = threadIdx.x;
    int wv = tid >> 6;
    int s = wv & 3, g = wv >> 2;
    int lane = tid & 63, q = lane >> 4, c = lane & 15;
    __shared__ alignas(16) u4v wl[4][32][64];       // 128 KiB: o-gate tiles
    __shared__ alignas(16) unsigned hbuf[2][128];   // h f16 pairs, dbuf
    __shared__ alignas(16) float sgp[256][4];       // hi-K raw partials
    const float* pb = pre + (size_t)(dir * 4 + b) * (1024 * 1024);
    const u4v* wsrc = (const u4v*)whb + (size_t)dir * 32768;

    // register-resident B-frags: tiles j=0..11, this wave's K-half
    u4v wr[12][4];
#pragma unroll
    for (int j = 0; j < 12; j++)
#pragma unroll
        for (int kx = 0; kx < 4; kx++)
            wr[j][kx] = wsrc[(size_t)((s + 4 * j) * 8 + 4 * g + kx) * 64 + lane];
    // LDS-resident o-gate tiles j=12..15 (slot = (j-12)*8 + kk)
#pragma unroll
    for (int j = 0; j < 4; j++)
#pragma unroll
        for (int kx = 0; kx < 4; kx++)
            wl[s][j * 8 + 4 * g + kx][lane] =
                wsrc[(size_t)((s + 48 + 4 * j) * 8 + 4 * g + kx) * 64 + lane];
    if (tid < 256) ((unsigned*)hbuf)[tid] = 0;
    float cst[4] = {0.f, 0.f, 0.f, 0.f};   // live for g==0, q==0
    __syncthreads();

#pragma unroll 1
    for (int t = 0; t < L_; ++t) {
        int row = dir ? (L_ - 1 - t) : t;
        int cur = t & 1;
        float pr[16];
        if (g == 0 && q == 0) {
            const float* prow = pb + (size_t)row * 1024 + 16 * s + c;
#pragma unroll
            for (int jj = 0; jj < 4; jj++)
#pragma unroll
                for (int gt = 0; gt < 4; gt++)
                    pr[jj * 4 + gt] = prow[64 * jj + 256 * gt];
        }
        const unsigned* hb = &hbuf[cur][0];
        float sv[16];
#pragma unroll
        for (int jj = 0; jj < 4; jj++) {
            f4v A0 = (f4v)0.f, A1 = (f4v)0.f, A2 = (f4v)0.f, A3 = (f4v)0.f;
#pragma unroll
            for (int kx = 0; kx < 4; kx++) {
                h8v a = __builtin_bit_cast(
                    h8v, *(const u4v*)(hb + (4 * g + kx) * 16 + q * 4));
                u4v lo = wl[s][jj * 8 + 4 * g + kx][lane];
                A0 = MF(a, wr[jj][kx], A0);          // i gate
                A1 = MF(a, wr[jj + 4][kx], A1);      // f gate
                A2 = MF(a, wr[jj + 8][kx], A2);      // g gate
                A3 = MF(a, lo, A3);                  // o gate (LDS tile)
            }
            if (g) {
                if (q == 0)
                    *(f4v*)&sgp[16 * s + c + 64 * jj][0] =
                        f4v{A0.x, A1.x, A2.x, A3.x};
            } else {
                sv[jj * 4 + 0] = A0.x; sv[jj * 4 + 1] = A1.x;
                sv[jj * 4 + 2] = A2.x; sv[jj * 4 + 3] = A3.x;
            }
        }
        __syncthreads();
        if (g == 0 && q == 0) {
#pragma unroll
            for (int jj = 0; jj < 4; jj++) {
                int u = 16 * s + c + 64 * jj;
                f4v S = *(const f4v*)&sgp[u][0];
                float ig = sv[jj * 4 + 0] + S.x + pr[jj * 4 + 0];
                float fg = sv[jj * 4 + 1] + S.y + pr[jj * 4 + 1];
                float gg = sv[jj * 4 + 2] + S.z + pr[jj * 4 + 2];
                float og = sv[jj * 4 + 3] + S.w + pr[jj * 4 + 3];
                float si = fast_sig(ig), sf = fast_sig(fg), so = fast_sig(og);
                cst[jj] = sf * cst[jj] + si * fast_tanh(gg);
                float h = so * fast_tanh(cst[jj]);
                ((_Float16*)hbuf)[(cur ^ 1) * 256 + u] = (_Float16)h;
                docs[((size_t)(b * L_ + row)) * D2_ + dir * H_ + u] = h;
            }
        }
        __syncthreads();
    }
}

// -------------------------------------------------- entity pooling e_map @ docs
__global__ __launch_bounds__(256) void k_pool(
    const float* __restrict__ emap, const float* __restrict__ docs,
    float* __restrict__ ent) {
    int n = blockIdx.x;                 // b*64 + e
    int b = n >> 6;
    __shared__ float sm[1024];
    for (int idx = threadIdx.x; idx < 1024; idx += 256)
        sm[idx] = emap[(size_t)n * 1024 + idx];
    __syncthreads();
    int d = threadIdx.x;
    float a0 = 0.f, a1 = 0.f;
    const float* db = docs + (size_t)b * L_ * D2_;
#pragma unroll 4
    for (int l = 0; l < L_; l++) {
        float mv = sm[l];
        a0 += mv * db[l * D2_ + d];
        a1 += mv * db[l * D2_ + d + 256];
    }
    ent[n * D2_ + d] = a0;
    ent[n * D2_ + d + 256] = a1;
}

// ------------------- convert bili_W fp32 [276][276][256] -> swizzled padded f16
__global__ __launch_bounds__(256) void k_cvt_w(
    const float* __restrict__ W, unsigned short* __restrict__ Wb) {
    unsigned gid = blockIdx.x * 256 + threadIdx.x;   // < 20,348,928
    unsigned t = gid & 7u;
    unsigned np = (gid >> 3) & 15u;
    unsigned q = (gid >> 7) & 3u;
    unsigned ns = (gid >> 9) & 15u;
    unsigned c = gid >> 13;
    unsigned i = c / 9u, jc = c - i * 9u;
    unsigned jp = jc * 32u + q * 8u + t;
    float v = (jp < 276u) ? W[((size_t)i * 276u + jp) * 256u + ns * 16u + np] : 0.f;
    Wb[gid] = f16bits(v);
}

// ------------------------------------------- per-relation messages relu(ent@W_rel)
__global__ __launch_bounds__(256) void k_msg(
    const float* __restrict__ ent, const float* __restrict__ wrel,
    float* __restrict__ m) {
    int n = blockIdx.x, r = blockIdx.y;
    __shared__ float se[512];
    for (int idx = threadIdx.x; idx < 512; idx += 256) se[idx] = ent[n * D2_ + idx];
    __syncthreads();
    int d = threadIdx.x;
    const float* W = wrel + (size_t)r * D2_ * D2_;
    float a0 = 0.f, a1 = 0.f;
#pragma unroll 4
    for (int k = 0; k < 512; k++) {
        float e = se[k];
        a0 += e * W[k * 512 + d];
        a1 += e * W[k * 512 + d + 256];
    }
    size_t o = ((size_t)(r * N_ + n)) * D2_;
    m[o + d] = fmaxf(a0, 0.f);
    m[o + d + 256] = fmaxf(a1, 0.f);
}

// --------------------------------------------------------- edge scatter-add
__global__ __launch_bounds__(256) void k_scatter(
    const int* __restrict__ esrc, const int* __restrict__ edst,
    const int* __restrict__ etyp, const float* __restrict__ m,
    float* __restrict__ agg) {
    int gid = blockIdx.x * 256 + threadIdx.x;   // E*128
    int e = gid >> 7, q = (gid & 127) << 2;
    int s = esrc[e], dn = edst[e], ty = etyp[e];
    const float4 v = *(const float4*)(m + ((size_t)(ty * N_ + s)) * D2_ + q);
    float* ap = agg + (size_t)dn * D2_ + q;
    atomicAdd(ap + 0, v.x); atomicAdd(ap + 1, v.y);
    atomicAdd(ap + 2, v.z); atomicAdd(ap + 3, v.w);
}

// ------------------------------------- hs/ts = relu(ent@Wself + agg@Wmsg + b)
__global__ __launch_bounds__(256) void k_hsts(
    const float* __restrict__ ent, const float* __restrict__ agg,
    const float* __restrict__ wsh, const float* __restrict__ wmh, const float* __restrict__ bh,
    const float* __restrict__ wst, const float* __restrict__ wmt, const float* __restrict__ bt,
    float* __restrict__ hs, float* __restrict__ ts) {
    int n = blockIdx.x, ty = blockIdx.y;
    const float* Ws = ty ? wst : wsh;
    const float* Wm = ty ? wmt : wmh;
    const float* bi = ty ? bt : bh;
    float* out = ty ? ts : hs;
    __shared__ float se[512], sa[512];
    for (int idx = threadIdx.x; idx < 512; idx += 256) {
        se[idx] = ent[n * 512 + idx];
        sa[idx] = agg[n * 512 + idx];
    }
    __syncthreads();
    int d = threadIdx.x;
    float a0 = bi[d], a1 = bi[d + 256];
#pragma unroll 2
    for (int k = 0; k < 512; k++) {
        float e = se[k], a = sa[k];
        a0 += e * Ws[k * 512 + d] + a * Wm[k * 512 + d];
        a1 += e * Ws[k * 512 + d + 256] + a * Wm[k * 512 + d + 256];
    }
    out[n * 512 + d] = fmaxf(a0, 0.f);
    out[n * 512 + d + 256] = fmaxf(a1, 0.f);
}

// --------------------- pair gather + projections -> f16 hd/td (288-pad) + hp*tp
__global__ __launch_bounds__(256) void k_pairs(
    const float* __restrict__ hs, const float* __restrict__ ts,
    const int* __restrict__ hts, const int* __restrict__ dht, const int* __restrict__ dth,
    const float* __restrict__ hW, const float* __restrict__ hb,
    const float* __restrict__ tW, const float* __restrict__ tb,
    const float* __restrict__ dis,
    unsigned short* __restrict__ hdb, unsigned short* __restrict__ tdb,
    float* __restrict__ hptp) {
    int bp = blockIdx.x;                // b*P + p
    int b = bp >> 9;
    int hi = hts[bp * 2], ti = hts[bp * 2 + 1];
    __shared__ float sh[512], st[512];
    const float* hr = hs + ((size_t)(b * NE_ + hi)) * D2_;
    const float* tr = ts + ((size_t)(b * NE_ + ti)) * D2_;
    for (int idx = threadIdx.x; idx < 512; idx += 256) {
        sh[idx] = hr[idx];
        st[idx] = tr[idx];
    }
    __syncthreads();
    int d = threadIdx.x;
    float ah = hb[d], at = tb[d];
#pragma unroll 4
    for (int k = 0; k < 512; k++) {
        ah += sh[k] * hW[k * H_ + d];
        at += st[k] * tW[k * H_ + d];
    }
    size_t rb = (size_t)bp * 288;
    hdb[rb + d] = f16bits(ah);
    tdb[rb + d] = f16bits(at);
    hptp[(size_t)bp * H_ + d] = ah * at;
    if (d < DD_) {
        hdb[rb + 256 + d] = f16bits(dis[dht[bp] * DD_ + d]);
        tdb[rb + 256 + d] = f16bits(dis[dth[bp] * DD_ + d]);
    }
    if (d < 12) {
        hdb[rb + 276 + d] = 0;
        tdb[rb + 276 + d] = 0;
    }
}

// -------------------- bilinear as MFMA GEMM: blacc[p,k] += A(p,ij) Wb(ij,k)
__global__ __launch_bounds__(512) void k_bili(
    const unsigned short* __restrict__ Wb, const unsigned short* __restrict__ hdb,
    const unsigned short* __restrict__ tdb, float* __restrict__ blacc) {
    int bx = blockIdx.x, kc = blockIdx.y;
    int i0 = kc * 17 + (kc < 4 ? kc : 4);
    int cnt = 17 + (kc < 4 ? 1 : 0);
    int steps = cnt * 9;
    int tid = threadIdx.x;
    int w = tid >> 6, lane = tid & 63, q = lane >> 4, n16 = lane & 15;

    __shared__ alignas(16) unsigned short Bs[2][8192];
    __shared__ unsigned short hds[128 * 18];

    for (int e = tid; e < 128 * 18; e += 512)
        hds[e] = hdb[(size_t)(bx * 128 + e / 18) * 288 + i0 + e % 18];

    int p = bx * 128 + w * 16 + n16;
    const u4v* tdsrc = (const u4v*)(tdb + (size_t)p * 288);
    TDreg td[9];
#pragma unroll
    for (int jc = 0; jc < 9; jc++) td[jc].u = tdsrc[jc * 4 + q];

    f4v acc[16];
#pragma unroll
    for (int i = 0; i < 16; i++) acc[i] = (f4v)0.f;

    const u4v* gsrc = (const u4v*)Wb + (size_t)(i0 * 9) * 1024 + tid * 2;
    u4v r0 = gsrc[0], r1 = gsrc[1];
    {
        u4v* bs0 = (u4v*)(&Bs[0][0]);
        bs0[tid * 2] = r0; bs0[tid * 2 + 1] = r1;
    }
    __syncthreads();

    int il = 0, jc = 0;
    for (int s = 0; s < steps; s++) {
        if (s + 1 < steps) {
            const u4v* gs = gsrc + (size_t)(s + 1) * 1024;
            r0 = gs[0]; r1 = gs[1];
        }
        unsigned short hraw = hds[(w * 16 + n16) * 18 + il];
        _Float16 hv = __builtin_bit_cast(_Float16, hraw);
        h2v hd2 = {hv, hv};
        AFrag af;
#pragma unroll
        for (int e2 = 0; e2 < 4; e2++) af.h[e2] = hd2 * td[jc].h[e2];
        const unsigned short* bsc = &Bs[s & 1][0];
#pragma unroll
        for (int ns = 0; ns < 16; ns++) {
            h8v bf = *(const h8v*)(bsc + ns * 512 + lane * 8);
            acc[ns] = __builtin_amdgcn_mfma_f32_16x16x32_f16(af.v, bf, acc[ns], 0, 0, 0);
        }
        if (s + 1 < steps) {
            u4v* bsn = (u4v*)(&Bs[(s + 1) & 1][0]);
            bsn[tid * 2] = r0; bsn[tid * 2 + 1] = r1;
        }
        __syncthreads();
        if (++jc == 9) { jc = 0; il++; }
    }

    float* dst = blacc + (size_t)(bx * 128 + w * 16 + q * 4) * 256 + n16;
#pragma unroll
    for (int ns = 0; ns < 16; ns++)
#pragma unroll
        for (int r = 0; r < 4; r++)
            atomicAdd(dst + (size_t)r * 256 + ns * 16, acc[ns][r]);
}

// ------------------- logits = [relu(blacc + bili_b) | hp*tp] @ out_W + out_b
__global__ __launch_bounds__(128) void k_final(
    const float* __restrict__ blacc, const float* __restrict__ bib,
    const float* __restrict__ hptp,
    const float* __restrict__ oW, const float* __restrict__ ob,
    float* __restrict__ out) {
    int bp = blockIdx.x;
    __shared__ float s[512];
    for (int idx = threadIdx.x; idx < 512; idx += 128)
        s[idx] = (idx < 256) ? fmaxf(blacc[(size_t)bp * 256 + idx] + bib[idx], 0.f)
                             : hptp[(size_t)bp * 256 + idx - 256];
    __syncthreads();
    int r = threadIdx.x;
    if (r >= REL_) return;
    float a = ob[r];
#pragma unroll 4
    for (int d = 0; d < 512; d++) a += s[d] * oW[d * REL_ + r];
    out[(size_t)bp * REL_ + r] = a;
}

extern "C" void kernel_launch(void* const* d_in, const int* in_sizes, int n_in,
                              void* d_out, int out_size, void* d_ws, size_t ws_size,
                              hipStream_t stream) {
    const float* e_map    = (const float*)d_in[0];
    const float* word_t   = (const float*)d_in[1];
    const float* coref_t  = (const float*)d_in[2];
    const float* ner_t    = (const float*)d_in[3];
    const float* Wi_f     = (const float*)d_in[4];
    const float* Wh_f     = (const float*)d_in[5];
    const float* b_f      = (const float*)d_in[6];
    const float* Wi_b     = (const float*)d_in[7];
    const float* Wh_b     = (const float*)d_in[8];
    const float* b_b      = (const float*)d_in[9];
    const float* W_rel    = (const float*)d_in[10];
    const float* W_self_h = (const float*)d_in[11];
    const float* W_msg_h  = (const float*)d_in[12];
    const float* b_h      = (const float*)d_in[13];
    const float* W_self_t = (const float*)d_in[14];
    const float* W_msg_t  = (const float*)d_in[15];
    const float* b_t      = (const float*)d_in[16];
    const float* head_W   = (const float*)d_in[17];
    const float* head_b   = (const float*)d_in[18];
    const float* tail_W   = (const float*)d_in[19];
    const float* tail_b   = (const float*)d_in[20];
    const float* dis_t    = (const float*)d_in[21];
    const float* bili_W   = (const float*)d_in[22];
    const float* bili_b   = (const float*)d_in[23];
    const float* out_W    = (const float*)d_in[24];
    const float* out_b    = (const float*)d_in[25];
    const int* ctx_idx = (const int*)d_in[26];
    const int* pos     = (const int*)d_in[27];
    const int* ctx_ner = (const int*)d_in[28];
    const int* hts     = (const int*)d_in[29];
    const int* dht     = (const int*)d_in[30];
    const int* dth     = (const int*)d_in[31];
    const int* esrc    = (const int*)d_in[32];
    const int* edst    = (const int*)d_in[33];
    const int* etyp    = (const int*)d_in[34];

    float* ws = (float*)d_ws;
    float* emb  = ws + OFF_EMB;
    float* pre  = ws + OFF_PRE;
    float* docs = ws + OFF_DOCS;
    unsigned* whp = (unsigned*)(ws + OFF_WHP);
    float* ent  = ws + OFF_ENT;
    float* m    = ws + OFF_M;
    float* agg  = ws + OFF_AGG;
    float* hsb  = ws + OFF_HS;
    float* tsb  = ws + OFF_TS;
    float* hptp = ws + OFF_HPTP;
    float* blacc = ws + OFF_BL;
    unsigned short* Wb  = (unsigned short*)(ws + OFF_WB_F16);
    unsigned short* hdb = (unsigned short*)(ws + OFF_HDB_F16);
    unsigned short* tdb = (unsigned short*)(ws + OFF_TDB_F16);
    float* out  = (float*)d_out;

    hipLaunchKernelGGL(k_embed, dim3(B_ * L_), dim3(192), 0, stream,
                       word_t, coref_t, ner_t, ctx_idx, pos, ctx_ner, emb);
    hipLaunchKernelGGL(k_pack_wh, dim3(1024), dim3(256), 0, stream, Wh_f, Wh_b, whp);
    hipLaunchKernelGGL(k_pregates, dim3(512, 2), dim3(256), 0, stream,
                       emb, Wi_f, b_f, Wi_b, b_b, pre);
    hipLaunchKernelGGL(k_lstm, dim3(8), dim3(512), 0, stream, pre, whp, docs);
    hipLaunchKernelGGL(k_pool, dim3(N_), dim3(256), 0, stream, e_map, docs, ent);
    // Wb overlays emb/pre/docs -> must come after k_pool
    hipLaunchKernelGGL(k_cvt_w, dim3(79488), dim3(256), 0, stream, bili_W, Wb);
    hipLaunchKernelGGL(k_msg, dim3(N_, R_), dim3(256), 0, stream, ent, W_rel, m);
    hipMemsetAsync(agg, 0, (size_t)N_ * D2_ * sizeof(float), stream);
    hipLaunchKernelGGL(k_scatter, dim3(E_ * 128 / 256), dim3(256), 0, stream,
                       esrc, edst, etyp, m, agg);
    hipLaunchKernelGGL(k_hsts, dim3(N_, 2), dim3(256), 0, stream,
                       ent, agg, W_self_h, W_msg_h, b_h, W_self_t, W_msg_t, b_t, hsb, tsb);
    hipLaunchKernelGGL(k_pairs, dim3(B_ * P_), dim3(256), 0, stream,
                       hsb, tsb, hts, dht, dth, head_W, head_b, tail_W, tail_b,
                       dis_t, hdb, tdb, hptp);
    hipMemsetAsync(blacc, 0, (size_t)2048 * 256 * sizeof(float), stream);
    hipLaunchKernelGGL(k_bili, dim3(16, 16), dim3(512), 0, stream, Wb, hdb, tdb, blacc);
    hipLaunchKernelGGL(k_final, dim3(B_ * P_), dim3(128), 0, stream,
                       blacc, bili_b, hptp, out_W, out_b, out);
}

// Round 4
// 2776.205 us; speedup vs baseline: 1.6599x; 1.6599x over previous
//
#include <hip/hip_runtime.h>
#include <cstdint>

#define B_   4
#define L_   1024
#define H_   256
#define NE_  64
#define P_   512
#define E_   65536
#define R_   4
#define DW_  100
#define DC_  20
#define DT_  20
#define DD_  20
#define REL_ 97
#define N_   256      // B*NE
#define D2_  512
#define DBI_ 276
#define DIN_ 140
#define G4_  1024     // 4*H

// workspace offsets in floats
#define OFF_EMB  0u
#define OFF_PRE  573440u
#define OFF_DOCS 8962048u
#define OFF_WHP  11059200u
#define OFF_ENT  11321344u
#define OFF_M    11452416u
#define OFF_AGG  11976704u
#define OFF_HS   12107776u
#define OFF_TS   12238848u
#define OFF_HD   12369920u
#define OFF_TD   12935168u
#define OFF_HPTP 13500416u
#define OFF_BL   14024704u
// f16 buffers overlaid on emb/pre/docs (dead after k_pool):
#define OFF_WB_F16   0u
#define OFF_HDB_F16  10174464u
#define OFF_TDB_F16  10469376u

typedef _Float16 h2v __attribute__((ext_vector_type(2)));
typedef _Float16 h8v __attribute__((ext_vector_type(8)));
typedef float f4v __attribute__((ext_vector_type(4)));
typedef unsigned int u4v __attribute__((ext_vector_type(4)));

union AFrag { h8v v; h2v h[4]; };
union TDreg { u4v u; h2v h[4]; };

__device__ __forceinline__ unsigned short f16bits(float x) {
    return __builtin_bit_cast(unsigned short, (_Float16)x);
}

// fast hw transcendentals: v_exp_f32 computes 2^x, v_rcp_f32 ~1ulp.
#if __has_builtin(__builtin_amdgcn_exp2f)
#define EXP2F __builtin_amdgcn_exp2f
#else
#define EXP2F exp2f
#endif
#if __has_builtin(__builtin_amdgcn_rcpf)
#define RCPF __builtin_amdgcn_rcpf
#else
#define RCPF(x) (1.0f / (x))
#endif

__device__ __forceinline__ float fast_sig(float x) {
    return RCPF(1.0f + EXP2F(x * -1.44269504f));
}
__device__ __forceinline__ float fast_tanh(float x) {
    return 1.0f - 2.0f * RCPF(EXP2F(x * 2.88539008f) + 1.0f);
}

__device__ __forceinline__ f4v MF(h8v a, u4v b, f4v c) {
    return __builtin_amdgcn_mfma_f32_16x16x32_f16(
        a, __builtin_bit_cast(h8v, b), c, 0, 0, 0);
}

// ---------------------------------------------------------------- embeddings
__global__ __launch_bounds__(192) void k_embed(
    const float* __restrict__ wt, const float* __restrict__ ct,
    const float* __restrict__ nt, const int* __restrict__ widx,
    const int* __restrict__ pidx, const int* __restrict__ nidx,
    float* __restrict__ emb) {
    int row = blockIdx.x;               // b*L + l
    int t = threadIdx.x;
    if (t >= DIN_) return;
    float v;
    if (t < DW_)            v = wt[(size_t)widx[row] * DW_ + t];
    else if (t < DW_ + DC_) v = ct[pidx[row] * DC_ + (t - DW_)];
    else                    v = nt[nidx[row] * DT_ + (t - DW_ - DC_)];
    emb[(size_t)row * DIN_ + t] = v;
}

// -------- pack Wh (both dirs) into MFMA B-fragment layout (f16 pairs)
// whp u32 index = (((dir*64 + n)*8 + kk)*64 + lane)*4 + m
// value: pack(f16(Wh[k0][col]), f16(Wh[k0+1][col]))
//   k0 = kk*32 + (lane>>4)*8 + 2m, col = n*16 + (lane&15)
// = per-lane B operand of v_mfma_f32_16x16x32_f16 for tile n, K-tile kk.
__global__ __launch_bounds__(256) void k_pack_wh(
    const float* __restrict__ whf, const float* __restrict__ whb,
    unsigned* __restrict__ whp) {
    unsigned gid = blockIdx.x * 256 + threadIdx.x;   // 2^18 total
    unsigned m    = gid & 3u;
    unsigned lane = (gid >> 2) & 63u;
    unsigned kk   = (gid >> 8) & 7u;
    unsigned n    = (gid >> 11) & 63u;
    unsigned dir  = gid >> 17;
    const float* src = dir ? whb : whf;
    unsigned k0  = kk * 32u + (lane >> 4) * 8u + 2u * m;
    unsigned col = n * 16u + (lane & 15u);
    unsigned lo = f16bits(src[(size_t)k0 * G4_ + col]);
    unsigned hi = f16bits(src[(size_t)(k0 + 1) * G4_ + col]);
    whp[gid] = (hi << 16) | lo;
}

// ----------------------------------------- pre-gates: emb @ Wi + b (both dirs)
__global__ __launch_bounds__(256) void k_pregates(
    const float* __restrict__ emb,
    const float* __restrict__ wif, const float* __restrict__ bf,
    const float* __restrict__ wib, const float* __restrict__ bb,
    float* __restrict__ pre) {
    int dir = blockIdx.y;
    const float* Wi   = dir ? wib : wif;
    const float* bias = dir ? bb : bf;
    int x8 = blockIdx.x * 8;            // 8 (b,l) rows per block
    __shared__ float se[8 * DIN_];
    for (int idx = threadIdx.x; idx < 8 * DIN_; idx += 256)
        se[idx] = emb[(size_t)(x8 + idx / DIN_) * DIN_ + idx % DIN_];
    __syncthreads();
    int t = threadIdx.x;
    float acc[8][4];
#pragma unroll
    for (int r = 0; r < 8; r++)
#pragma unroll
        for (int q = 0; q < 4; q++) acc[r][q] = bias[t + q * 256];
    for (int k = 0; k < DIN_; k++) {
        float w0 = Wi[k * G4_ + t];
        float w1 = Wi[k * G4_ + t + 256];
        float w2 = Wi[k * G4_ + t + 512];
        float w3 = Wi[k * G4_ + t + 768];
#pragma unroll
        for (int r = 0; r < 8; r++) {
            float e = se[r * DIN_ + k];
            acc[r][0] += e * w0; acc[r][1] += e * w1;
            acc[r][2] += e * w2; acc[r][3] += e * w3;
        }
    }
#pragma unroll
    for (int r = 0; r < 8; r++) {
        float* dst = pre + ((size_t)(dir * 4096 + x8 + r)) * G4_ + t;
        dst[0] = acc[r][0]; dst[256] = acc[r][1];
        dst[512] = acc[r][2]; dst[768] = acc[r][3];
    }
}

// --------------- BiLSTM v5: MFMA recurrence, 2 waves/SIMD (256-reg cap via
// amdgpu_waves_per_eu(2); launch_bounds 2nd-arg semantics burned us in R3).
// 8 blocks (dir x batch) x 512 threads = 8 waves: wave = (col-set s in 0..3,
// K-half g in 0..1). Set s owns tiles n = s+4j; wave covers kk in [4g,4g+4).
// Unit u = 16s+c+64jj uses tile-rows {jj, jj+4, jj+8, jj+12} (i,f,g,o).
// i/f/g tiles: K-half frags in VGPR (192 regs). o tiles: LDS (128 KiB).
// M=1 MFMA replicates the gate value in every lane/reg of the C-frag, so
// lane roles are free to choose:
//   q<2  lanes: activation owners for act_jj = 2g + (q&1)   (sv[4], pr[4])
//   q>=2 lanes: publish partner-wave partials for pub_jj = 2(1-g) + (q&1)
// One sgp exchange + ONE activation chain per lane -> short serial tail.
__global__ __launch_bounds__(512)
__attribute__((amdgpu_waves_per_eu(2)))
void k_lstm(
    const float* __restrict__ pre, const unsigned* __restrict__ whb,
    float* __restrict__ docs) {
    int dir = blockIdx.x >> 2, b = blockIdx.x & 3;
    int tid = threadIdx.x;
    int wv = tid >> 6;
    int s = wv & 3, g = wv >> 2;
    int lane = tid & 63, q = lane >> 4, c = lane & 15;
    __shared__ alignas(16) u4v wl[4][32][64];       // 128 KiB: o-gate tiles
    __shared__ alignas(16) unsigned hbuf[2][128];   // h f16 pairs, dbuf
    __shared__ alignas(16) float sgp[256][4];       // partner-K partials
    const float* pb = pre + (size_t)(dir * 4 + b) * (1024 * 1024);
    const u4v* wsrc = (const u4v*)whb + (size_t)dir * 32768;

    // register-resident B-frags: tile-rows j=0..11 (i/f/g), this wave's K-half
    u4v wr[12][4];
#pragma unroll
    for (int j = 0; j < 12; j++)
#pragma unroll
        for (int kx = 0; kx < 4; kx++)
            wr[j][kx] = wsrc[(size_t)((s + 4 * j) * 8 + 4 * g + kx) * 64 + lane];
    // LDS-resident o-gate tile-rows j=12..15 (slot = (j-12)*8 + kk)
#pragma unroll
    for (int j = 0; j < 4; j++)
#pragma unroll
        for (int kx = 0; kx < 4; kx++)
            wl[s][j * 8 + 4 * g + kx][lane] =
                wsrc[(size_t)((s + 48 + 4 * j) * 8 + 4 * g + kx) * 64 + lane];
    if (tid < 256) ((unsigned*)hbuf)[tid] = 0;

    int act_jj = 2 * g + (q & 1);           // meaningful for q<2
    int pub_jj = 2 * (1 - g) + (q & 1);     // meaningful for q>=2
    int u_act = 16 * s + c + 64 * act_jj;
    bool is_act = (q < 2);
    float cst = 0.f;                        // cell state, q<2 lanes
    __syncthreads();

#pragma unroll 1
    for (int t = 0; t < L_; ++t) {
        int row = dir ? (L_ - 1 - t) : t;
        int cur = t & 1;
        float pr0, pr1, pr2, pr3;
        if (is_act) {
            const float* prow = pb + (size_t)row * 1024 + u_act;
            pr0 = prow[0]; pr1 = prow[256]; pr2 = prow[512]; pr3 = prow[768];
        }
        const unsigned* hb = &hbuf[cur][0];
        float sv0, sv1, sv2, sv3;
#pragma unroll
        for (int jj = 0; jj < 4; jj++) {
            f4v A0 = (f4v)0.f, A1 = (f4v)0.f, A2 = (f4v)0.f, A3 = (f4v)0.f;
#pragma unroll
            for (int kx = 0; kx < 4; kx++) {
                h8v a = __builtin_bit_cast(
                    h8v, *(const u4v*)(hb + (4 * g + kx) * 16 + q * 4));
                u4v lo = wl[s][jj * 8 + 4 * g + kx][lane];
                A0 = MF(a, wr[jj][kx], A0);          // i gate
                A1 = MF(a, wr[jj + 4][kx], A1);      // f gate
                A2 = MF(a, wr[jj + 8][kx], A2);      // g gate
                A3 = MF(a, lo, A3);                  // o gate (LDS tile)
            }
            if (q >= 2 && pub_jj == jj)
                *(f4v*)&sgp[16 * s + c + 64 * jj][0] = f4v{A0.x, A1.x, A2.x, A3.x};
            if (is_act && act_jj == jj) {
                sv0 = A0.x; sv1 = A1.x; sv2 = A2.x; sv3 = A3.x;
            }
        }
        __syncthreads();
        if (is_act) {
            f4v S = *(const f4v*)&sgp[u_act][0];
            float ig = sv0 + S.x + pr0;
            float fg = sv1 + S.y + pr1;
            float gg = sv2 + S.z + pr2;
            float og = sv3 + S.w + pr3;
            float si = fast_sig(ig), sf = fast_sig(fg), so = fast_sig(og);
            cst = sf * cst + si * fast_tanh(gg);
            float h = so * fast_tanh(cst);
            ((_Float16*)hbuf)[(cur ^ 1) * 256 + u_act] = (_Float16)h;
            docs[((size_t)(b * L_ + row)) * D2_ + dir * H_ + u_act] = h;
        }
        __syncthreads();
    }
}

// -------------------------------------------------- entity pooling e_map @ docs
__global__ __launch_bounds__(256) void k_pool(
    const float* __restrict__ emap, const float* __restrict__ docs,
    float* __restrict__ ent) {
    int n = blockIdx.x;                 // b*64 + e
    int b = n >> 6;
    __shared__ float sm[1024];
    for (int idx = threadIdx.x; idx < 1024; idx += 256)
        sm[idx] = emap[(size_t)n * 1024 + idx];
    __syncthreads();
    int d = threadIdx.x;
    float a0 = 0.f, a1 = 0.f;
    const float* db = docs + (size_t)b * L_ * D2_;
#pragma unroll 4
    for (int l = 0; l < L_; l++) {
        float mv = sm[l];
        a0 += mv * db[l * D2_ + d];
        a1 += mv * db[l * D2_ + d + 256];
    }
    ent[n * D2_ + d] = a0;
    ent[n * D2_ + d + 256] = a1;
}

// ------------------- convert bili_W fp32 [276][276][256] -> swizzled padded f16
__global__ __launch_bounds__(256) void k_cvt_w(
    const float* __restrict__ W, unsigned short* __restrict__ Wb) {
    unsigned gid = blockIdx.x * 256 + threadIdx.x;   // < 20,348,928
    unsigned t = gid & 7u;
    unsigned np = (gid >> 3) & 15u;
    unsigned q = (gid >> 7) & 3u;
    unsigned ns = (gid >> 9) & 15u;
    unsigned c = gid >> 13;
    unsigned i = c / 9u, jc = c - i * 9u;
    unsigned jp = jc * 32u + q * 8u + t;
    float v = (jp < 276u) ? W[((size_t)i * 276u + jp) * 256u + ns * 16u + np] : 0.f;
    Wb[gid] = f16bits(v);
}

// ------------------------------------------- per-relation messages relu(ent@W_rel)
__global__ __launch_bounds__(256) void k_msg(
    const float* __restrict__ ent, const float* __restrict__ wrel,
    float* __restrict__ m) {
    int n = blockIdx.x, r = blockIdx.y;
    __shared__ float se[512];
    for (int idx = threadIdx.x; idx < 512; idx += 256) se[idx] = ent[n * D2_ + idx];
    __syncthreads();
    int d = threadIdx.x;
    const float* W = wrel + (size_t)r * D2_ * D2_;
    float a0 = 0.f, a1 = 0.f;
#pragma unroll 4
    for (int k = 0; k < 512; k++) {
        float e = se[k];
        a0 += e * W[k * 512 + d];
        a1 += e * W[k * 512 + d + 256];
    }
    size_t o = ((size_t)(r * N_ + n)) * D2_;
    m[o + d] = fmaxf(a0, 0.f);
    m[o + d + 256] = fmaxf(a1, 0.f);
}

// --------------------------------------------------------- edge scatter-add
__global__ __launch_bounds__(256) void k_scatter(
    const int* __restrict__ esrc, const int* __restrict__ edst,
    const int* __restrict__ etyp, const float* __restrict__ m,
    float* __restrict__ agg) {
    int gid = blockIdx.x * 256 + threadIdx.x;   // E*128
    int e = gid >> 7, q = (gid & 127) << 2;
    int s = esrc[e], dn = edst[e], ty = etyp[e];
    const float4 v = *(const float4*)(m + ((size_t)(ty * N_ + s)) * D2_ + q);
    float* ap = agg + (size_t)dn * D2_ + q;
    atomicAdd(ap + 0, v.x); atomicAdd(ap + 1, v.y);
    atomicAdd(ap + 2, v.z); atomicAdd(ap + 3, v.w);
}

// ------------------------------------- hs/ts = relu(ent@Wself + agg@Wmsg + b)
__global__ __launch_bounds__(256) void k_hsts(
    const float* __restrict__ ent, const float* __restrict__ agg,
    const float* __restrict__ wsh, const float* __restrict__ wmh, const float* __restrict__ bh,
    const float* __restrict__ wst, const float* __restrict__ wmt, const float* __restrict__ bt,
    float* __restrict__ hs, float* __restrict__ ts) {
    int n = blockIdx.x, ty = blockIdx.y;
    const float* Ws = ty ? wst : wsh;
    const float* Wm = ty ? wmt : wmh;
    const float* bi = ty ? bt : bh;
    float* out = ty ? ts : hs;
    __shared__ float se[512], sa[512];
    for (int idx = threadIdx.x; idx < 512; idx += 256) {
        se[idx] = ent[n * 512 + idx];
        sa[idx] = agg[n * 512 + idx];
    }
    __syncthreads();
    int d = threadIdx.x;
    float a0 = bi[d], a1 = bi[d + 256];
#pragma unroll 2
    for (int k = 0; k < 512; k++) {
        float e = se[k], a = sa[k];
        a0 += e * Ws[k * 512 + d] + a * Wm[k * 512 + d];
        a1 += e * Ws[k * 512 + d + 256] + a * Wm[k * 512 + d + 256];
    }
    out[n * 512 + d] = fmaxf(a0, 0.f);
    out[n * 512 + d + 256] = fmaxf(a1, 0.f);
}

// --------------------- pair gather + projections -> f16 hd/td (288-pad) + hp*tp
__global__ __launch_bounds__(256) void k_pairs(
    const float* __restrict__ hs, const float* __restrict__ ts,
    const int* __restrict__ hts, const int* __restrict__ dht, const int* __restrict__ dth,
    const float* __restrict__ hW, const float* __restrict__ hb,
    const float* __restrict__ tW, const float* __restrict__ tb,
    const float* __restrict__ dis,
    unsigned short* __restrict__ hdb, unsigned short* __restrict__ tdb,
    float* __restrict__ hptp) {
    int bp = blockIdx.x;                // b*P + p
    int b = bp >> 9;
    int hi = hts[bp * 2], ti = hts[bp * 2 + 1];
    __shared__ float sh[512], st[512];
    const float* hr = hs + ((size_t)(b * NE_ + hi)) * D2_;
    const float* tr = ts + ((size_t)(b * NE_ + ti)) * D2_;
    for (int idx = threadIdx.x; idx < 512; idx += 256) {
        sh[idx] = hr[idx];
        st[idx] = tr[idx];
    }
    __syncthreads();
    int d = threadIdx.x;
    float ah = hb[d], at = tb[d];
#pragma unroll 4
    for (int k = 0; k < 512; k++) {
        ah += sh[k] * hW[k * H_ + d];
        at += st[k] * tW[k * H_ + d];
    }
    size_t rb = (size_t)bp * 288;
    hdb[rb + d] = f16bits(ah);
    tdb[rb + d] = f16bits(at);
    hptp[(size_t)bp * H_ + d] = ah * at;
    if (d < DD_) {
        hdb[rb + 256 + d] = f16bits(dis[dht[bp] * DD_ + d]);
        tdb[rb + 256 + d] = f16bits(dis[dth[bp] * DD_ + d]);
    }
    if (d < 12) {
        hdb[rb + 276 + d] = 0;
        tdb[rb + 276 + d] = 0;
    }
}

// -------------------- bilinear as MFMA GEMM: blacc[p,k] += A(p,ij) Wb(ij,k)
__global__ __launch_bounds__(512) void k_bili(
    const unsigned short* __restrict__ Wb, const unsigned short* __restrict__ hdb,
    const unsigned short* __restrict__ tdb, float* __restrict__ blacc) {
    int bx = blockIdx.x, kc = blockIdx.y;
    int i0 = kc * 17 + (kc < 4 ? kc : 4);
    int cnt = 17 + (kc < 4 ? 1 : 0);
    int steps = cnt * 9;
    int tid = threadIdx.x;
    int w = tid >> 6, lane = tid & 63, q = lane >> 4, n16 = lane & 15;

    __shared__ alignas(16) unsigned short Bs[2][8192];
    __shared__ unsigned short hds[128 * 18];

    for (int e = tid; e < 128 * 18; e += 512)
        hds[e] = hdb[(size_t)(bx * 128 + e / 18) * 288 + i0 + e % 18];

    int p = bx * 128 + w * 16 + n16;
    const u4v* tdsrc = (const u4v*)(tdb + (size_t)p * 288);
    TDreg td[9];
#pragma unroll
    for (int jc = 0; jc < 9; jc++) td[jc].u = tdsrc[jc * 4 + q];

    f4v acc[16];
#pragma unroll
    for (int i = 0; i < 16; i++) acc[i] = (f4v)0.f;

    const u4v* gsrc = (const u4v*)Wb + (size_t)(i0 * 9) * 1024 + tid * 2;
    u4v r0 = gsrc[0], r1 = gsrc[1];
    {
        u4v* bs0 = (u4v*)(&Bs[0][0]);
        bs0[tid * 2] = r0; bs0[tid * 2 + 1] = r1;
    }
    __syncthreads();

    int il = 0, jc = 0;
    for (int s = 0; s < steps; s++) {
        if (s + 1 < steps) {
            const u4v* gs = gsrc + (size_t)(s + 1) * 1024;
            r0 = gs[0]; r1 = gs[1];
        }
        unsigned short hraw = hds[(w * 16 + n16) * 18 + il];
        _Float16 hv = __builtin_bit_cast(_Float16, hraw);
        h2v hd2 = {hv, hv};
        AFrag af;
#pragma unroll
        for (int e2 = 0; e2 < 4; e2++) af.h[e2] = hd2 * td[jc].h[e2];
        const unsigned short* bsc = &Bs[s & 1][0];
#pragma unroll
        for (int ns = 0; ns < 16; ns++) {
            h8v bf = *(const h8v*)(bsc + ns * 512 + lane * 8);
            acc[ns] = __builtin_amdgcn_mfma_f32_16x16x32_f16(af.v, bf, acc[ns], 0, 0, 0);
        }
        if (s + 1 < steps) {
            u4v* bsn = (u4v*)(&Bs[(s + 1) & 1][0]);
            bsn[tid * 2] = r0; bsn[tid * 2 + 1] = r1;
        }
        __syncthreads();
        if (++jc == 9) { jc = 0; il++; }
    }

    float* dst = blacc + (size_t)(bx * 128 + w * 16 + q * 4) * 256 + n16;
#pragma unroll
    for (int ns = 0; ns < 16; ns++)
#pragma unroll
        for (int r = 0; r < 4; r++)
            atomicAdd(dst + (size_t)r * 256 + ns * 16, acc[ns][r]);
}

// ------------------- logits = [relu(blacc + bili_b) | hp*tp] @ out_W + out_b
__global__ __launch_bounds__(128) void k_final(
    const float* __restrict__ blacc, const float* __restrict__ bib,
    const float* __restrict__ hptp,
    const float* __restrict__ oW, const float* __restrict__ ob,
    float* __restrict__ out) {
    int bp = blockIdx.x;
    __shared__ float s[512];
    for (int idx = threadIdx.x; idx < 512; idx += 128)
        s[idx] = (idx < 256) ? fmaxf(blacc[(size_t)bp * 256 + idx] + bib[idx], 0.f)
                             : hptp[(size_t)bp * 256 + idx - 256];
    __syncthreads();
    int r = threadIdx.x;
    if (r >= REL_) return;
    float a = ob[r];
#pragma unroll 4
    for (int d = 0; d < 512; d++) a += s[d] * oW[d * REL_ + r];
    out[(size_t)bp * REL_ + r] = a;
}

extern "C" void kernel_launch(void* const* d_in, const int* in_sizes, int n_in,
                              void* d_out, int out_size, void* d_ws, size_t ws_size,
                              hipStream_t stream) {
    const float* e_map    = (const float*)d_in[0];
    const float* word_t   = (const float*)d_in[1];
    const float* coref_t  = (const float*)d_in[2];
    const float* ner_t    = (const float*)d_in[3];
    const float* Wi_f     = (const float*)d_in[4];
    const float* Wh_f     = (const float*)d_in[5];
    const float* b_f      = (const float*)d_in[6];
    const float* Wi_b     = (const float*)d_in[7];
    const float* Wh_b     = (const float*)d_in[8];
    const float* b_b      = (const float*)d_in[9];
    const float* W_rel    = (const float*)d_in[10];
    const float* W_self_h = (const float*)d_in[11];
    const float* W_msg_h  = (const float*)d_in[12];
    const float* b_h      = (const float*)d_in[13];
    const float* W_self_t = (const float*)d_in[14];
    const float* W_msg_t  = (const float*)d_in[15];
    const float* b_t      = (const float*)d_in[16];
    const float* head_W   = (const float*)d_in[17];
    const float* head_b   = (const float*)d_in[18];
    const float* tail_W   = (const float*)d_in[19];
    const float* tail_b   = (const float*)d_in[20];
    const float* dis_t    = (const float*)d_in[21];
    const float* bili_W   = (const float*)d_in[22];
    const float* bili_b   = (const float*)d_in[23];
    const float* out_W    = (const float*)d_in[24];
    const float* out_b    = (const float*)d_in[25];
    const int* ctx_idx = (const int*)d_in[26];
    const int* pos     = (const int*)d_in[27];
    const int* ctx_ner = (const int*)d_in[28];
    const int* hts     = (const int*)d_in[29];
    const int* dht     = (const int*)d_in[30];
    const int* dth     = (const int*)d_in[31];
    const int* esrc    = (const int*)d_in[32];
    const int* edst    = (const int*)d_in[33];
    const int* etyp    = (const int*)d_in[34];

    float* ws = (float*)d_ws;
    float* emb  = ws + OFF_EMB;
    float* pre  = ws + OFF_PRE;
    float* docs = ws + OFF_DOCS;
    unsigned* whp = (unsigned*)(ws + OFF_WHP);
    float* ent  = ws + OFF_ENT;
    float* m    = ws + OFF_M;
    float* agg  = ws + OFF_AGG;
    float* hsb  = ws + OFF_HS;
    float* tsb  = ws + OFF_TS;
    float* hptp = ws + OFF_HPTP;
    float* blacc = ws + OFF_BL;
    unsigned short* Wb  = (unsigned short*)(ws + OFF_WB_F16);
    unsigned short* hdb = (unsigned short*)(ws + OFF_HDB_F16);
    unsigned short* tdb = (unsigned short*)(ws + OFF_TDB_F16);
    float* out  = (float*)d_out;

    hipLaunchKernelGGL(k_embed, dim3(B_ * L_), dim3(192), 0, stream,
                       word_t, coref_t, ner_t, ctx_idx, pos, ctx_ner, emb);
    hipLaunchKernelGGL(k_pack_wh, dim3(1024), dim3(256), 0, stream, Wh_f, Wh_b, whp);
    hipLaunchKernelGGL(k_pregates, dim3(512, 2), dim3(256), 0, stream,
                       emb, Wi_f, b_f, Wi_b, b_b, pre);
    hipLaunchKernelGGL(k_lstm, dim3(8), dim3(512), 0, stream, pre, whp, docs);
    hipLaunchKernelGGL(k_pool, dim3(N_), dim3(256), 0, stream, e_map, docs, ent);
    // Wb overlays emb/pre/docs -> must come after k_pool
    hipLaunchKernelGGL(k_cvt_w, dim3(79488), dim3(256), 0, stream, bili_W, Wb);
    hipLaunchKernelGGL(k_msg, dim3(N_, R_), dim3(256), 0, stream, ent, W_rel, m);
    hipMemsetAsync(agg, 0, (size_t)N_ * D2_ * sizeof(float), stream);
    hipLaunchKernelGGL(k_scatter, dim3(E_ * 128 / 256), dim3(256), 0, stream,
                       esrc, edst, etyp, m, agg);
    hipLaunchKernelGGL(k_hsts, dim3(N_, 2), dim3(256), 0, stream,
                       ent, agg, W_self_h, W_msg_h, b_h, W_self_t, W_msg_t, b_t, hsb, tsb);
    hipLaunchKernelGGL(k_pairs, dim3(B_ * P_), dim3(256), 0, stream,
                       hsb, tsb, hts, dht, dth, head_W, head_b, tail_W, tail_b,
                       dis_t, hdb, tdb, hptp);
    hipMemsetAsync(blacc, 0, (size_t)2048 * 256 * sizeof(float), stream);
    hipLaunchKernelGGL(k_bili, dim3(16, 16), dim3(512), 0, stream, Wb, hdb, tdb, blacc);
    hipLaunchKernelGGL(k_final, dim3(B_ * P_), dim3(128), 0, stream,
                       blacc, bili_b, hptp, out_W, out_b, out);
}

// Round 5
// 2588.805 us; speedup vs baseline: 1.7800x; 1.0724x over previous
//
#include <hip/hip_runtime.h>
#include <cstdint>

#define B_   4
#define L_   1024
#define H_   256
#define NE_  64
#define P_   512
#define E_   65536
#define R_   4
#define DW_  100
#define DC_  20
#define DT_  20
#define DD_  20
#define REL_ 97
#define N_   256      // B*NE
#define D2_  512
#define DBI_ 276
#define DIN_ 140
#define G4_  1024     // 4*H

// workspace offsets in floats
#define OFF_EMB  0u
#define OFF_PRE  573440u
#define OFF_DOCS 8962048u
#define OFF_WHP  11059200u
#define OFF_ENT  11321344u
#define OFF_M    11452416u
#define OFF_AGG  11976704u
#define OFF_HS   12107776u
#define OFF_TS   12238848u
#define OFF_HD   12369920u
#define OFF_TD   12935168u
#define OFF_HPTP 13500416u
#define OFF_BL   14024704u
// f16 buffers overlaid on emb/pre/docs (dead after k_pool):
#define OFF_WB_F16   0u
#define OFF_HDB_F16  10174464u
#define OFF_TDB_F16  10469376u

typedef _Float16 h2v __attribute__((ext_vector_type(2)));
typedef _Float16 h8v __attribute__((ext_vector_type(8)));
typedef float f4v __attribute__((ext_vector_type(4)));
typedef unsigned int u4v __attribute__((ext_vector_type(4)));

union AFrag { h8v v; h2v h[4]; };
union TDreg { u4v u; h2v h[4]; };

__device__ __forceinline__ unsigned short f16bits(float x) {
    return __builtin_bit_cast(unsigned short, (_Float16)x);
}

// fast hw transcendentals: v_exp_f32 computes 2^x, v_rcp_f32 ~1ulp.
#if __has_builtin(__builtin_amdgcn_exp2f)
#define EXP2F __builtin_amdgcn_exp2f
#else
#define EXP2F exp2f
#endif
#if __has_builtin(__builtin_amdgcn_rcpf)
#define RCPF __builtin_amdgcn_rcpf
#else
#define RCPF(x) (1.0f / (x))
#endif

__device__ __forceinline__ float fast_sig(float x) {
    return RCPF(1.0f + EXP2F(x * -1.44269504f));
}
__device__ __forceinline__ float fast_tanh(float x) {
    return 1.0f - 2.0f * RCPF(EXP2F(x * 2.88539008f) + 1.0f);
}

__device__ __forceinline__ f4v MF(h8v a, u4v b, f4v c) {
    return __builtin_amdgcn_mfma_f32_16x16x32_f16(
        a, __builtin_bit_cast(h8v, b), c, 0, 0, 0);
}

// ---------------------------------------------------------------- embeddings
__global__ __launch_bounds__(192) void k_embed(
    const float* __restrict__ wt, const float* __restrict__ ct,
    const float* __restrict__ nt, const int* __restrict__ widx,
    const int* __restrict__ pidx, const int* __restrict__ nidx,
    float* __restrict__ emb) {
    int row = blockIdx.x;               // b*L + l
    int t = threadIdx.x;
    if (t >= DIN_) return;
    float v;
    if (t < DW_)            v = wt[(size_t)widx[row] * DW_ + t];
    else if (t < DW_ + DC_) v = ct[pidx[row] * DC_ + (t - DW_)];
    else                    v = nt[nidx[row] * DT_ + (t - DW_ - DC_)];
    emb[(size_t)row * DIN_ + t] = v;
}

// -------- pack Wh (both dirs) into MFMA B-fragment layout (f16 pairs)
// whp u32 index = (((dir*64 + n)*8 + kk)*64 + lane)*4 + m
// value: pack(f16(Wh[k0][col]), f16(Wh[k0+1][col]))
//   k0 = kk*32 + (lane>>4)*8 + 2m, col = n*16 + (lane&15)
// = per-lane B operand of v_mfma_f32_16x16x32_f16 for tile n, K-tile kk.
__global__ __launch_bounds__(256) void k_pack_wh(
    const float* __restrict__ whf, const float* __restrict__ whb,
    unsigned* __restrict__ whp) {
    unsigned gid = blockIdx.x * 256 + threadIdx.x;   // 2^18 total
    unsigned m    = gid & 3u;
    unsigned lane = (gid >> 2) & 63u;
    unsigned kk   = (gid >> 8) & 7u;
    unsigned n    = (gid >> 11) & 63u;
    unsigned dir  = gid >> 17;
    const float* src = dir ? whb : whf;
    unsigned k0  = kk * 32u + (lane >> 4) * 8u + 2u * m;
    unsigned col = n * 16u + (lane & 15u);
    unsigned lo = f16bits(src[(size_t)k0 * G4_ + col]);
    unsigned hi = f16bits(src[(size_t)(k0 + 1) * G4_ + col]);
    whp[gid] = (hi << 16) | lo;
}

// ----------------------------------------- pre-gates: emb @ Wi + b (both dirs)
__global__ __launch_bounds__(256) void k_pregates(
    const float* __restrict__ emb,
    const float* __restrict__ wif, const float* __restrict__ bf,
    const float* __restrict__ wib, const float* __restrict__ bb,
    float* __restrict__ pre) {
    int dir = blockIdx.y;
    const float* Wi   = dir ? wib : wif;
    const float* bias = dir ? bb : bf;
    int x8 = blockIdx.x * 8;            // 8 (b,l) rows per block
    __shared__ float se[8 * DIN_];
    for (int idx = threadIdx.x; idx < 8 * DIN_; idx += 256)
        se[idx] = emb[(size_t)(x8 + idx / DIN_) * DIN_ + idx % DIN_];
    __syncthreads();
    int t = threadIdx.x;
    float acc[8][4];
#pragma unroll
    for (int r = 0; r < 8; r++)
#pragma unroll
        for (int q = 0; q < 4; q++) acc[r][q] = bias[t + q * 256];
    for (int k = 0; k < DIN_; k++) {
        float w0 = Wi[k * G4_ + t];
        float w1 = Wi[k * G4_ + t + 256];
        float w2 = Wi[k * G4_ + t + 512];
        float w3 = Wi[k * G4_ + t + 768];
#pragma unroll
        for (int r = 0; r < 8; r++) {
            float e = se[r * DIN_ + k];
            acc[r][0] += e * w0; acc[r][1] += e * w1;
            acc[r][2] += e * w2; acc[r][3] += e * w3;
        }
    }
#pragma unroll
    for (int r = 0; r < 8; r++) {
        float* dst = pre + ((size_t)(dir * 4096 + x8 + r)) * G4_ + t;
        dst[0] = acc[r][0]; dst[256] = acc[r][1];
        dst[512] = acc[r][2]; dst[768] = acc[r][3];
    }
}

// --------------- BiLSTM v6: full-K waves, one barrier per step.
// 8 blocks (dir x batch) x 512 threads = 8 waves, 2 waves/SIMD (waves_per_eu(2);
// weights land in AGPRs per R4 — VGPR_Count 128 is the arch half).
// Wave w owns unit-groups j' = 2w, 2w+1: tiles {j', j'+16, j'+32, j'+48}
// (i,f,g,o gate columns of units u = 16j'+c), with ALL 8 K-tiles -> no
// cross-wave partial exchange, no sgp, ONE barrier per step (h double-buffer:
// act writes hbuf[nxt]; nothing reads hbuf[nxt] until after the barrier).
// i/f/g weights in regs (48 u4v = 192), o-gate tiles in LDS (128 KiB).
// kk-outer loop: h-frag read ONCE per kk (8 broadcast b128/thread/step),
// o-gate reads 16 per-lane b128/thread/step. M=1 MFMA with broadcast A
// replicates each gate value across all C rows -> q<2 lanes run activations
// (one unit each), exp2-based, write h (f16) + docs.
__global__ __launch_bounds__(512)
__attribute__((amdgpu_waves_per_eu(2)))
void k_lstm(
    const float* __restrict__ pre, const unsigned* __restrict__ whb,
    float* __restrict__ docs) {
    int dir = blockIdx.x >> 2, b = blockIdx.x & 3;
    int tid = threadIdx.x;
    int w = tid >> 6;
    int lane = tid & 63, q = lane >> 4, c = lane & 15;
    __shared__ alignas(16) u4v wl[16][8][64];       // 128 KiB o-gate tiles
    __shared__ alignas(16) unsigned hbuf[2][128];   // h f16 pairs, dbuf
    const float* pb = pre + (size_t)(dir * 4 + b) * (1024 * 1024);
    const u4v* wsrc = (const u4v*)whb + (size_t)dir * 32768;

    // register-resident i/f/g weights: wr[j2][gate][kk], tile n = 2w+j2+16*gate
    u4v wr[2][3][8];
#pragma unroll
    for (int j2 = 0; j2 < 2; j2++)
#pragma unroll
        for (int gt = 0; gt < 3; gt++)
#pragma unroll
            for (int kk = 0; kk < 8; kk++)
                wr[j2][gt][kk] =
                    wsrc[(size_t)((2 * w + j2 + 16 * gt) * 8 + kk) * 64 + lane];
    // LDS-resident o-gate tiles (n = 2w+j2+48)
#pragma unroll
    for (int j2 = 0; j2 < 2; j2++)
#pragma unroll
        for (int kk = 0; kk < 8; kk++)
            wl[2 * w + j2][kk][lane] =
                wsrc[(size_t)((2 * w + j2 + 48) * 8 + kk) * 64 + lane];
    if (tid < 256) ((unsigned*)hbuf)[tid] = 0;

    bool is_act = (q < 2);
    int j2a = q & 1;                        // this act lane's unit-group
    int u_act = 32 * w + 16 * j2a + c;      // unit index in [0,256)
    float cst = 0.f;
    __syncthreads();

#pragma unroll 1
    for (int t = 0; t < L_; ++t) {
        int row = dir ? (L_ - 1 - t) : t;
        int cur = t & 1;
        float pr0, pr1, pr2, pr3;
        if (is_act) {                       // issued early, used after MFMAs
            const float* prow = pb + (size_t)row * 1024 + u_act;
            pr0 = prow[0]; pr1 = prow[256]; pr2 = prow[512]; pr3 = prow[768];
        }
        const u4v* hb4 = (const u4v*)&hbuf[cur][0];
        f4v a00 = (f4v)0.f, a01 = (f4v)0.f, a02 = (f4v)0.f, a03 = (f4v)0.f;
        f4v a10 = (f4v)0.f, a11 = (f4v)0.f, a12 = (f4v)0.f, a13 = (f4v)0.f;
#pragma unroll
        for (int kk = 0; kk < 8; kk++) {
            h8v a = __builtin_bit_cast(h8v, hb4[kk * 4 + q]);   // broadcast h
            u4v l0 = wl[2 * w][kk][lane];
            u4v l1 = wl[2 * w + 1][kk][lane];
            a00 = MF(a, wr[0][0][kk], a00);     // i, group 2w
            a01 = MF(a, wr[0][1][kk], a01);     // f
            a02 = MF(a, wr[0][2][kk], a02);     // g
            a03 = MF(a, l0, a03);               // o (LDS)
            a10 = MF(a, wr[1][0][kk], a10);     // i, group 2w+1
            a11 = MF(a, wr[1][1][kk], a11);     // f
            a12 = MF(a, wr[1][2][kk], a12);     // g
            a13 = MF(a, l1, a13);               // o (LDS)
        }
        if (is_act) {
            float ig = (j2a ? a10.x : a00.x) + pr0;
            float fg = (j2a ? a11.x : a01.x) + pr1;
            float gg = (j2a ? a12.x : a02.x) + pr2;
            float og = (j2a ? a13.x : a03.x) + pr3;
            float si = fast_sig(ig), sf = fast_sig(fg), so = fast_sig(og);
            cst = sf * cst + si * fast_tanh(gg);
            float h = so * fast_tanh(cst);
            ((_Float16*)hbuf)[(cur ^ 1) * 256 + u_act] = (_Float16)h;
            docs[((size_t)(b * L_ + row)) * D2_ + dir * H_ + u_act] = h;
        }
        __syncthreads();                    // single barrier: publish h(t+1)
    }
}

// -------------------------------------------------- entity pooling e_map @ docs
__global__ __launch_bounds__(256) void k_pool(
    const float* __restrict__ emap, const float* __restrict__ docs,
    float* __restrict__ ent) {
    int n = blockIdx.x;                 // b*64 + e
    int b = n >> 6;
    __shared__ float sm[1024];
    for (int idx = threadIdx.x; idx < 1024; idx += 256)
        sm[idx] = emap[(size_t)n * 1024 + idx];
    __syncthreads();
    int d = threadIdx.x;
    float a0 = 0.f, a1 = 0.f;
    const float* db = docs + (size_t)b * L_ * D2_;
#pragma unroll 4
    for (int l = 0; l < L_; l++) {
        float mv = sm[l];
        a0 += mv * db[l * D2_ + d];
        a1 += mv * db[l * D2_ + d + 256];
    }
    ent[n * D2_ + d] = a0;
    ent[n * D2_ + d + 256] = a1;
}

// ------------------- convert bili_W fp32 [276][276][256] -> swizzled padded f16
__global__ __launch_bounds__(256) void k_cvt_w(
    const float* __restrict__ W, unsigned short* __restrict__ Wb) {
    unsigned gid = blockIdx.x * 256 + threadIdx.x;   // < 20,348,928
    unsigned t = gid & 7u;
    unsigned np = (gid >> 3) & 15u;
    unsigned q = (gid >> 7) & 3u;
    unsigned ns = (gid >> 9) & 15u;
    unsigned c = gid >> 13;
    unsigned i = c / 9u, jc = c - i * 9u;
    unsigned jp = jc * 32u + q * 8u + t;
    float v = (jp < 276u) ? W[((size_t)i * 276u + jp) * 256u + ns * 16u + np] : 0.f;
    Wb[gid] = f16bits(v);
}

// ------------------------------------------- per-relation messages relu(ent@W_rel)
__global__ __launch_bounds__(256) void k_msg(
    const float* __restrict__ ent, const float* __restrict__ wrel,
    float* __restrict__ m) {
    int n = blockIdx.x, r = blockIdx.y;
    __shared__ float se[512];
    for (int idx = threadIdx.x; idx < 512; idx += 256) se[idx] = ent[n * D2_ + idx];
    __syncthreads();
    int d = threadIdx.x;
    const float* W = wrel + (size_t)r * D2_ * D2_;
    float a0 = 0.f, a1 = 0.f;
#pragma unroll 4
    for (int k = 0; k < 512; k++) {
        float e = se[k];
        a0 += e * W[k * 512 + d];
        a1 += e * W[k * 512 + d + 256];
    }
    size_t o = ((size_t)(r * N_ + n)) * D2_;
    m[o + d] = fmaxf(a0, 0.f);
    m[o + d + 256] = fmaxf(a1, 0.f);
}

// --------------------------------------------------------- edge scatter-add
__global__ __launch_bounds__(256) void k_scatter(
    const int* __restrict__ esrc, const int* __restrict__ edst,
    const int* __restrict__ etyp, const float* __restrict__ m,
    float* __restrict__ agg) {
    int gid = blockIdx.x * 256 + threadIdx.x;   // E*128
    int e = gid >> 7, q = (gid & 127) << 2;
    int s = esrc[e], dn = edst[e], ty = etyp[e];
    const float4 v = *(const float4*)(m + ((size_t)(ty * N_ + s)) * D2_ + q);
    float* ap = agg + (size_t)dn * D2_ + q;
    atomicAdd(ap + 0, v.x); atomicAdd(ap + 1, v.y);
    atomicAdd(ap + 2, v.z); atomicAdd(ap + 3, v.w);
}

// ------------------------------------- hs/ts = relu(ent@Wself + agg@Wmsg + b)
__global__ __launch_bounds__(256) void k_hsts(
    const float* __restrict__ ent, const float* __restrict__ agg,
    const float* __restrict__ wsh, const float* __restrict__ wmh, const float* __restrict__ bh,
    const float* __restrict__ wst, const float* __restrict__ wmt, const float* __restrict__ bt,
    float* __restrict__ hs, float* __restrict__ ts) {
    int n = blockIdx.x, ty = blockIdx.y;
    const float* Ws = ty ? wst : wsh;
    const float* Wm = ty ? wmt : wmh;
    const float* bi = ty ? bt : bh;
    float* out = ty ? ts : hs;
    __shared__ float se[512], sa[512];
    for (int idx = threadIdx.x; idx < 512; idx += 256) {
        se[idx] = ent[n * 512 + idx];
        sa[idx] = agg[n * 512 + idx];
    }
    __syncthreads();
    int d = threadIdx.x;
    float a0 = bi[d], a1 = bi[d + 256];
#pragma unroll 2
    for (int k = 0; k < 512; k++) {
        float e = se[k], a = sa[k];
        a0 += e * Ws[k * 512 + d] + a * Wm[k * 512 + d];
        a1 += e * Ws[k * 512 + d + 256] + a * Wm[k * 512 + d + 256];
    }
    out[n * 512 + d] = fmaxf(a0, 0.f);
    out[n * 512 + d + 256] = fmaxf(a1, 0.f);
}

// --------------------- pair gather + projections -> f16 hd/td (288-pad) + hp*tp
__global__ __launch_bounds__(256) void k_pairs(
    const float* __restrict__ hs, const float* __restrict__ ts,
    const int* __restrict__ hts, const int* __restrict__ dht, const int* __restrict__ dth,
    const float* __restrict__ hW, const float* __restrict__ hb,
    const float* __restrict__ tW, const float* __restrict__ tb,
    const float* __restrict__ dis,
    unsigned short* __restrict__ hdb, unsigned short* __restrict__ tdb,
    float* __restrict__ hptp) {
    int bp = blockIdx.x;                // b*P + p
    int b = bp >> 9;
    int hi = hts[bp * 2], ti = hts[bp * 2 + 1];
    __shared__ float sh[512], st[512];
    const float* hr = hs + ((size_t)(b * NE_ + hi)) * D2_;
    const float* tr = ts + ((size_t)(b * NE_ + ti)) * D2_;
    for (int idx = threadIdx.x; idx < 512; idx += 256) {
        sh[idx] = hr[idx];
        st[idx] = tr[idx];
    }
    __syncthreads();
    int d = threadIdx.x;
    float ah = hb[d], at = tb[d];
#pragma unroll 4
    for (int k = 0; k < 512; k++) {
        ah += sh[k] * hW[k * H_ + d];
        at += st[k] * tW[k * H_ + d];
    }
    size_t rb = (size_t)bp * 288;
    hdb[rb + d] = f16bits(ah);
    tdb[rb + d] = f16bits(at);
    hptp[(size_t)bp * H_ + d] = ah * at;
    if (d < DD_) {
        hdb[rb + 256 + d] = f16bits(dis[dht[bp] * DD_ + d]);
        tdb[rb + 256 + d] = f16bits(dis[dth[bp] * DD_ + d]);
    }
    if (d < 12) {
        hdb[rb + 276 + d] = 0;
        tdb[rb + 276 + d] = 0;
    }
}

// -------------------- bilinear as MFMA GEMM: blacc[p,k] += A(p,ij) Wb(ij,k)
__global__ __launch_bounds__(512) void k_bili(
    const unsigned short* __restrict__ Wb, const unsigned short* __restrict__ hdb,
    const unsigned short* __restrict__ tdb, float* __restrict__ blacc) {
    int bx = blockIdx.x, kc = blockIdx.y;
    int i0 = kc * 17 + (kc < 4 ? kc : 4);
    int cnt = 17 + (kc < 4 ? 1 : 0);
    int steps = cnt * 9;
    int tid = threadIdx.x;
    int w = tid >> 6, lane = tid & 63, q = lane >> 4, n16 = lane & 15;

    __shared__ alignas(16) unsigned short Bs[2][8192];
    __shared__ unsigned short hds[128 * 18];

    for (int e = tid; e < 128 * 18; e += 512)
        hds[e] = hdb[(size_t)(bx * 128 + e / 18) * 288 + i0 + e % 18];

    int p = bx * 128 + w * 16 + n16;
    const u4v* tdsrc = (const u4v*)(tdb + (size_t)p * 288);
    TDreg td[9];
#pragma unroll
    for (int jc = 0; jc < 9; jc++) td[jc].u = tdsrc[jc * 4 + q];

    f4v acc[16];
#pragma unroll
    for (int i = 0; i < 16; i++) acc[i] = (f4v)0.f;

    const u4v* gsrc = (const u4v*)Wb + (size_t)(i0 * 9) * 1024 + tid * 2;
    u4v r0 = gsrc[0], r1 = gsrc[1];
    {
        u4v* bs0 = (u4v*)(&Bs[0][0]);
        bs0[tid * 2] = r0; bs0[tid * 2 + 1] = r1;
    }
    __syncthreads();

    int il = 0, jc = 0;
    for (int s = 0; s < steps; s++) {
        if (s + 1 < steps) {
            const u4v* gs = gsrc + (size_t)(s + 1) * 1024;
            r0 = gs[0]; r1 = gs[1];
        }
        unsigned short hraw = hds[(w * 16 + n16) * 18 + il];
        _Float16 hv = __builtin_bit_cast(_Float16, hraw);
        h2v hd2 = {hv, hv};
        AFrag af;
#pragma unroll
        for (int e2 = 0; e2 < 4; e2++) af.h[e2] = hd2 * td[jc].h[e2];
        const unsigned short* bsc = &Bs[s & 1][0];
#pragma unroll
        for (int ns = 0; ns < 16; ns++) {
            h8v bf = *(const h8v*)(bsc + ns * 512 + lane * 8);
            acc[ns] = __builtin_amdgcn_mfma_f32_16x16x32_f16(af.v, bf, acc[ns], 0, 0, 0);
        }
        if (s + 1 < steps) {
            u4v* bsn = (u4v*)(&Bs[(s + 1) & 1][0]);
            bsn[tid * 2] = r0; bsn[tid * 2 + 1] = r1;
        }
        __syncthreads();
        if (++jc == 9) { jc = 0; il++; }
    }

    float* dst = blacc + (size_t)(bx * 128 + w * 16 + q * 4) * 256 + n16;
#pragma unroll
    for (int ns = 0; ns < 16; ns++)
#pragma unroll
        for (int r = 0; r < 4; r++)
            atomicAdd(dst + (size_t)r * 256 + ns * 16, acc[ns][r]);
}

// ------------------- logits = [relu(blacc + bili_b) | hp*tp] @ out_W + out_b
__global__ __launch_bounds__(128) void k_final(
    const float* __restrict__ blacc, const float* __restrict__ bib,
    const float* __restrict__ hptp,
    const float* __restrict__ oW, const float* __restrict__ ob,
    float* __restrict__ out) {
    int bp = blockIdx.x;
    __shared__ float s[512];
    for (int idx = threadIdx.x; idx < 512; idx += 128)
        s[idx] = (idx < 256) ? fmaxf(blacc[(size_t)bp * 256 + idx] + bib[idx], 0.f)
                             : hptp[(size_t)bp * 256 + idx - 256];
    __syncthreads();
    int r = threadIdx.x;
    if (r >= REL_) return;
    float a = ob[r];
#pragma unroll 4
    for (int d = 0; d < 512; d++) a += s[d] * oW[d * REL_ + r];
    out[(size_t)bp * REL_ + r] = a;
}

extern "C" void kernel_launch(void* const* d_in, const int* in_sizes, int n_in,
                              void* d_out, int out_size, void* d_ws, size_t ws_size,
                              hipStream_t stream) {
    const float* e_map    = (const float*)d_in[0];
    const float* word_t   = (const float*)d_in[1];
    const float* coref_t  = (const float*)d_in[2];
    const float* ner_t    = (const float*)d_in[3];
    const float* Wi_f     = (const float*)d_in[4];
    const float* Wh_f     = (const float*)d_in[5];
    const float* b_f      = (const float*)d_in[6];
    const float* Wi_b     = (const float*)d_in[7];
    const float* Wh_b     = (const float*)d_in[8];
    const float* b_b      = (const float*)d_in[9];
    const float* W_rel    = (const float*)d_in[10];
    const float* W_self_h = (const float*)d_in[11];
    const float* W_msg_h  = (const float*)d_in[12];
    const float* b_h      = (const float*)d_in[13];
    const float* W_self_t = (const float*)d_in[14];
    const float* W_msg_t  = (const float*)d_in[15];
    const float* b_t      = (const float*)d_in[16];
    const float* head_W   = (const float*)d_in[17];
    const float* head_b   = (const float*)d_in[18];
    const float* tail_W   = (const float*)d_in[19];
    const float* tail_b   = (const float*)d_in[20];
    const float* dis_t    = (const float*)d_in[21];
    const float* bili_W   = (const float*)d_in[22];
    const float* bili_b   = (const float*)d_in[23];
    const float* out_W    = (const float*)d_in[24];
    const float* out_b    = (const float*)d_in[25];
    const int* ctx_idx = (const int*)d_in[26];
    const int* pos     = (const int*)d_in[27];
    const int* ctx_ner = (const int*)d_in[28];
    const int* hts     = (const int*)d_in[29];
    const int* dht     = (const int*)d_in[30];
    const int* dth     = (const int*)d_in[31];
    const int* esrc    = (const int*)d_in[32];
    const int* edst    = (const int*)d_in[33];
    const int* etyp    = (const int*)d_in[34];

    float* ws = (float*)d_ws;
    float* emb  = ws + OFF_EMB;
    float* pre  = ws + OFF_PRE;
    float* docs = ws + OFF_DOCS;
    unsigned* whp = (unsigned*)(ws + OFF_WHP);
    float* ent  = ws + OFF_ENT;
    float* m    = ws + OFF_M;
    float* agg  = ws + OFF_AGG;
    float* hsb  = ws + OFF_HS;
    float* tsb  = ws + OFF_TS;
    float* hptp = ws + OFF_HPTP;
    float* blacc = ws + OFF_BL;
    unsigned short* Wb  = (unsigned short*)(ws + OFF_WB_F16);
    unsigned short* hdb = (unsigned short*)(ws + OFF_HDB_F16);
    unsigned short* tdb = (unsigned short*)(ws + OFF_TDB_F16);
    float* out  = (float*)d_out;

    hipLaunchKernelGGL(k_embed, dim3(B_ * L_), dim3(192), 0, stream,
                       word_t, coref_t, ner_t, ctx_idx, pos, ctx_ner, emb);
    hipLaunchKernelGGL(k_pack_wh, dim3(1024), dim3(256), 0, stream, Wh_f, Wh_b, whp);
    hipLaunchKernelGGL(k_pregates, dim3(512, 2), dim3(256), 0, stream,
                       emb, Wi_f, b_f, Wi_b, b_b, pre);
    hipLaunchKernelGGL(k_lstm, dim3(8), dim3(512), 0, stream, pre, whp, docs);
    hipLaunchKernelGGL(k_pool, dim3(N_), dim3(256), 0, stream, e_map, docs, ent);
    // Wb overlays emb/pre/docs -> must come after k_pool
    hipLaunchKernelGGL(k_cvt_w, dim3(79488), dim3(256), 0, stream, bili_W, Wb);
    hipLaunchKernelGGL(k_msg, dim3(N_, R_), dim3(256), 0, stream, ent, W_rel, m);
    hipMemsetAsync(agg, 0, (size_t)N_ * D2_ * sizeof(float), stream);
    hipLaunchKernelGGL(k_scatter, dim3(E_ * 128 / 256), dim3(256), 0, stream,
                       esrc, edst, etyp, m, agg);
    hipLaunchKernelGGL(k_hsts, dim3(N_, 2), dim3(256), 0, stream,
                       ent, agg, W_self_h, W_msg_h, b_h, W_self_t, W_msg_t, b_t, hsb, tsb);
    hipLaunchKernelGGL(k_pairs, dim3(B_ * P_), dim3(256), 0, stream,
                       hsb, tsb, hts, dht, dth, head_W, head_b, tail_W, tail_b,
                       dis_t, hdb, tdb, hptp);
    hipMemsetAsync(blacc, 0, (size_t)2048 * 256 * sizeof(float), stream);
    hipLaunchKernelGGL(k_bili, dim3(16, 16), dim3(512), 0, stream, Wb, hdb, tdb, blacc);
    hipLaunchKernelGGL(k_final, dim3(B_ * P_), dim3(128), 0, stream,
                       blacc, bili_b, hptp, out_W, out_b, out);
}

// Round 6
// 2207.940 us; speedup vs baseline: 2.0871x; 1.1725x over previous
//
#include <hip/hip_runtime.h>
#include <cstdint>

#define B_   4
#define L_   1024
#define H_   256
#define NE_  64
#define P_   512
#define E_   65536
#define R_   4
#define DW_  100
#define DC_  20
#define DT_  20
#define DD_  20
#define REL_ 97
#define N_   256      // B*NE
#define D2_  512
#define DBI_ 276
#define DIN_ 140
#define G4_  1024     // 4*H

// workspace offsets in floats
#define OFF_EMB  0u
#define OFF_PRE  573440u
#define OFF_DOCS 8962048u
#define OFF_WHP  11059200u
#define OFF_ENT  11321344u
#define OFF_M    11452416u
#define OFF_AGG  11976704u
#define OFF_HS   12107776u
#define OFF_TS   12238848u
#define OFF_HD   12369920u   // dead f32 region -> scatter aux (ints)
#define OFF_TD   12935168u
#define OFF_HPTP 13500416u
#define OFF_BL   14024704u
// f16 buffers overlaid on emb/pre/docs (dead after k_pool):
#define OFF_WB_F16   0u
#define OFF_HDB_F16  10174464u
#define OFF_TDB_F16  10469376u

typedef _Float16 h2v __attribute__((ext_vector_type(2)));
typedef _Float16 h8v __attribute__((ext_vector_type(8)));
typedef float f4v __attribute__((ext_vector_type(4)));
typedef unsigned int u4v __attribute__((ext_vector_type(4)));

union AFrag { h8v v; h2v h[4]; };
union TDreg { u4v u; h2v h[4]; };

__device__ __forceinline__ unsigned short f16bits(float x) {
    return __builtin_bit_cast(unsigned short, (_Float16)x);
}

// fast hw transcendentals: v_exp_f32 computes 2^x, v_rcp_f32 ~1ulp.
#if __has_builtin(__builtin_amdgcn_exp2f)
#define EXP2F __builtin_amdgcn_exp2f
#else
#define EXP2F exp2f
#endif
#if __has_builtin(__builtin_amdgcn_rcpf)
#define RCPF __builtin_amdgcn_rcpf
#else
#define RCPF(x) (1.0f / (x))
#endif

__device__ __forceinline__ float fast_sig(float x) {
    return RCPF(1.0f + EXP2F(x * -1.44269504f));
}
__device__ __forceinline__ float fast_tanh(float x) {
    return 1.0f - 2.0f * RCPF(EXP2F(x * 2.88539008f) + 1.0f);
}

__device__ __forceinline__ f4v MF(h8v a, u4v b, f4v c) {
    return __builtin_amdgcn_mfma_f32_16x16x32_f16(
        a, __builtin_bit_cast(h8v, b), c, 0, 0, 0);
}

// ---------------------------------------------------------------- embeddings
__global__ __launch_bounds__(192) void k_embed(
    const float* __restrict__ wt, const float* __restrict__ ct,
    const float* __restrict__ nt, const int* __restrict__ widx,
    const int* __restrict__ pidx, const int* __restrict__ nidx,
    float* __restrict__ emb) {
    int row = blockIdx.x;               // b*L + l
    int t = threadIdx.x;
    if (t >= DIN_) return;
    float v;
    if (t < DW_)            v = wt[(size_t)widx[row] * DW_ + t];
    else if (t < DW_ + DC_) v = ct[pidx[row] * DC_ + (t - DW_)];
    else                    v = nt[nidx[row] * DT_ + (t - DW_ - DC_)];
    emb[(size_t)row * DIN_ + t] = v;
}

// -------- pack Wh (both dirs) into MFMA B-fragment layout (f16 pairs)
// whp u32 index = (((dir*64 + n)*8 + kk)*64 + lane)*4 + m
// value: pack(f16(Wh[k0][col]), f16(Wh[k0+1][col]))
//   k0 = kk*32 + (lane>>4)*8 + 2m, col = n*16 + (lane&15)
// = per-lane B operand of v_mfma_f32_16x16x32_f16 for tile n, K-tile kk.
__global__ __launch_bounds__(256) void k_pack_wh(
    const float* __restrict__ whf, const float* __restrict__ whb,
    unsigned* __restrict__ whp) {
    unsigned gid = blockIdx.x * 256 + threadIdx.x;   // 2^18 total
    unsigned m    = gid & 3u;
    unsigned lane = (gid >> 2) & 63u;
    unsigned kk   = (gid >> 8) & 7u;
    unsigned n    = (gid >> 11) & 63u;
    unsigned dir  = gid >> 17;
    const float* src = dir ? whb : whf;
    unsigned k0  = kk * 32u + (lane >> 4) * 8u + 2u * m;
    unsigned col = n * 16u + (lane & 15u);
    unsigned lo = f16bits(src[(size_t)k0 * G4_ + col]);
    unsigned hi = f16bits(src[(size_t)(k0 + 1) * G4_ + col]);
    whp[gid] = (hi << 16) | lo;
}

// ----------------------------------------- pre-gates: emb @ Wi + b (both dirs)
__global__ __launch_bounds__(256) void k_pregates(
    const float* __restrict__ emb,
    const float* __restrict__ wif, const float* __restrict__ bf,
    const float* __restrict__ wib, const float* __restrict__ bb,
    float* __restrict__ pre) {
    int dir = blockIdx.y;
    const float* Wi   = dir ? wib : wif;
    const float* bias = dir ? bb : bf;
    int x8 = blockIdx.x * 8;            // 8 (b,l) rows per block
    __shared__ float se[8 * DIN_];
    for (int idx = threadIdx.x; idx < 8 * DIN_; idx += 256)
        se[idx] = emb[(size_t)(x8 + idx / DIN_) * DIN_ + idx % DIN_];
    __syncthreads();
    int t = threadIdx.x;
    float acc[8][4];
#pragma unroll
    for (int r = 0; r < 8; r++)
#pragma unroll
        for (int q = 0; q < 4; q++) acc[r][q] = bias[t + q * 256];
    for (int k = 0; k < DIN_; k++) {
        float w0 = Wi[k * G4_ + t];
        float w1 = Wi[k * G4_ + t + 256];
        float w2 = Wi[k * G4_ + t + 512];
        float w3 = Wi[k * G4_ + t + 768];
#pragma unroll
        for (int r = 0; r < 8; r++) {
            float e = se[r * DIN_ + k];
            acc[r][0] += e * w0; acc[r][1] += e * w1;
            acc[r][2] += e * w2; acc[r][3] += e * w3;
        }
    }
#pragma unroll
    for (int r = 0; r < 8; r++) {
        float* dst = pre + ((size_t)(dir * 4096 + x8 + r)) * G4_ + t;
        dst[0] = acc[r][0]; dst[256] = acc[r][1];
        dst[512] = acc[r][2]; dst[768] = acc[r][3];
    }
}

// --------------- BiLSTM v6 (frozen from R5): full-K waves, one barrier/step.
// 8 blocks (dir x batch) x 512 threads = 8 waves, 2 waves/SIMD. Wave w owns
// unit-groups 2w, 2w+1; i/f/g weights in regs (48 u4v, AGPR-backed), o-gate
// tiles in LDS. ~3000 cyc/step, DS-pipe-bound; reg-resident fraction (75%)
// is at the structural cap (CU regfile 512 KB == Wh size).
__global__ __launch_bounds__(512)
__attribute__((amdgpu_waves_per_eu(2)))
void k_lstm(
    const float* __restrict__ pre, const unsigned* __restrict__ whb,
    float* __restrict__ docs) {
    int dir = blockIdx.x >> 2, b = blockIdx.x & 3;
    int tid = threadIdx.x;
    int w = tid >> 6;
    int lane = tid & 63, q = lane >> 4, c = lane & 15;
    __shared__ alignas(16) u4v wl[16][8][64];       // 128 KiB o-gate tiles
    __shared__ alignas(16) unsigned hbuf[2][128];   // h f16 pairs, dbuf
    const float* pb = pre + (size_t)(dir * 4 + b) * (1024 * 1024);
    const u4v* wsrc = (const u4v*)whb + (size_t)dir * 32768;

    // register-resident i/f/g weights: wr[j2][gate][kk], tile n = 2w+j2+16*gate
    u4v wr[2][3][8];
#pragma unroll
    for (int j2 = 0; j2 < 2; j2++)
#pragma unroll
        for (int gt = 0; gt < 3; gt++)
#pragma unroll
            for (int kk = 0; kk < 8; kk++)
                wr[j2][gt][kk] =
                    wsrc[(size_t)((2 * w + j2 + 16 * gt) * 8 + kk) * 64 + lane];
    // LDS-resident o-gate tiles (n = 2w+j2+48)
#pragma unroll
    for (int j2 = 0; j2 < 2; j2++)
#pragma unroll
        for (int kk = 0; kk < 8; kk++)
            wl[2 * w + j2][kk][lane] =
                wsrc[(size_t)((2 * w + j2 + 48) * 8 + kk) * 64 + lane];
    if (tid < 256) ((unsigned*)hbuf)[tid] = 0;

    bool is_act = (q < 2);
    int j2a = q & 1;                        // this act lane's unit-group
    int u_act = 32 * w + 16 * j2a + c;      // unit index in [0,256)
    float cst = 0.f;
    __syncthreads();

#pragma unroll 1
    for (int t = 0; t < L_; ++t) {
        int row = dir ? (L_ - 1 - t) : t;
        int cur = t & 1;
        float pr0, pr1, pr2, pr3;
        if (is_act) {                       // issued early, used after MFMAs
            const float* prow = pb + (size_t)row * 1024 + u_act;
            pr0 = prow[0]; pr1 = prow[256]; pr2 = prow[512]; pr3 = prow[768];
        }
        const u4v* hb4 = (const u4v*)&hbuf[cur][0];
        f4v a00 = (f4v)0.f, a01 = (f4v)0.f, a02 = (f4v)0.f, a03 = (f4v)0.f;
        f4v a10 = (f4v)0.f, a11 = (f4v)0.f, a12 = (f4v)0.f, a13 = (f4v)0.f;
#pragma unroll
        for (int kk = 0; kk < 8; kk++) {
            h8v a = __builtin_bit_cast(h8v, hb4[kk * 4 + q]);   // broadcast h
            u4v l0 = wl[2 * w][kk][lane];
            u4v l1 = wl[2 * w + 1][kk][lane];
            a00 = MF(a, wr[0][0][kk], a00);     // i, group 2w
            a01 = MF(a, wr[0][1][kk], a01);     // f
            a02 = MF(a, wr[0][2][kk], a02);     // g
            a03 = MF(a, l0, a03);               // o (LDS)
            a10 = MF(a, wr[1][0][kk], a10);     // i, group 2w+1
            a11 = MF(a, wr[1][1][kk], a11);     // f
            a12 = MF(a, wr[1][2][kk], a12);     // g
            a13 = MF(a, l1, a13);               // o (LDS)
        }
        if (is_act) {
            float ig = (j2a ? a10.x : a00.x) + pr0;
            float fg = (j2a ? a11.x : a01.x) + pr1;
            float gg = (j2a ? a12.x : a02.x) + pr2;
            float og = (j2a ? a13.x : a03.x) + pr3;
            float si = fast_sig(ig), sf = fast_sig(fg), so = fast_sig(og);
            cst = sf * cst + si * fast_tanh(gg);
            float h = so * fast_tanh(cst);
            ((_Float16*)hbuf)[(cur ^ 1) * 256 + u_act] = (_Float16)h;
            docs[((size_t)(b * L_ + row)) * D2_ + dir * H_ + u_act] = h;
        }
        __syncthreads();                    // single barrier: publish h(t+1)
    }
}

// -------------------------------------------------- entity pooling e_map @ docs
__global__ __launch_bounds__(256) void k_pool(
    const float* __restrict__ emap, const float* __restrict__ docs,
    float* __restrict__ ent) {
    int n = blockIdx.x;                 // b*64 + e
    int b = n >> 6;
    __shared__ float sm[1024];
    for (int idx = threadIdx.x; idx < 1024; idx += 256)
        sm[idx] = emap[(size_t)n * 1024 + idx];
    __syncthreads();
    int d = threadIdx.x;
    float a0 = 0.f, a1 = 0.f;
    const float* db = docs + (size_t)b * L_ * D2_;
#pragma unroll 4
    for (int l = 0; l < L_; l++) {
        float mv = sm[l];
        a0 += mv * db[l * D2_ + d];
        a1 += mv * db[l * D2_ + d + 256];
    }
    ent[n * D2_ + d] = a0;
    ent[n * D2_ + d + 256] = a1;
}

// ------------------- convert bili_W fp32 [276][276][256] -> swizzled padded f16
__global__ __launch_bounds__(256) void k_cvt_w(
    const float* __restrict__ W, unsigned short* __restrict__ Wb) {
    unsigned gid = blockIdx.x * 256 + threadIdx.x;   // < 20,348,928
    unsigned t = gid & 7u;
    unsigned np = (gid >> 3) & 15u;
    unsigned q = (gid >> 7) & 3u;
    unsigned ns = (gid >> 9) & 15u;
    unsigned c = gid >> 13;
    unsigned i = c / 9u, jc = c - i * 9u;
    unsigned jp = jc * 32u + q * 8u + t;
    float v = (jp < 276u) ? W[((size_t)i * 276u + jp) * 256u + ns * 16u + np] : 0.f;
    Wb[gid] = f16bits(v);
}

// ------------------------------------------- per-relation messages relu(ent@W_rel)
__global__ __launch_bounds__(256) void k_msg(
    const float* __restrict__ ent, const float* __restrict__ wrel,
    float* __restrict__ m) {
    int n = blockIdx.x, r = blockIdx.y;
    __shared__ float se[512];
    for (int idx = threadIdx.x; idx < 512; idx += 256) se[idx] = ent[n * D2_ + idx];
    __syncthreads();
    int d = threadIdx.x;
    const float* W = wrel + (size_t)r * D2_ * D2_;
    float a0 = 0.f, a1 = 0.f;
#pragma unroll 4
    for (int k = 0; k < 512; k++) {
        float e = se[k];
        a0 += e * W[k * 512 + d];
        a1 += e * W[k * 512 + d + 256];
    }
    size_t o = ((size_t)(r * N_ + n)) * D2_;
    m[o + d] = fmaxf(a0, 0.f);
    m[o + d + 256] = fmaxf(a1, 0.f);
}

// ---------------- scatter-add replacement: bucket by destination, then dense
// reduce (no f32 atomics). aux layout (ints) in the dead OFF_HD region:
//   cnt[256] | pos[E] | slot[E] | offs[256]
__global__ __launch_bounds__(256) void k_sc_count(
    const int* __restrict__ edst, int* __restrict__ cnt, int* __restrict__ pos) {
    int e = blockIdx.x * 256 + threadIdx.x;
    pos[e] = atomicAdd(&cnt[edst[e]], 1);
}

__global__ __launch_bounds__(256) void k_sc_scan(
    const int* __restrict__ cnt, int* __restrict__ offs) {
    __shared__ int s[256];
    int t = threadIdx.x;
    int my = cnt[t];
    s[t] = my;
    __syncthreads();
    for (int d = 1; d < 256; d <<= 1) {
        int v = (t >= d) ? s[t - d] : 0;
        __syncthreads();
        s[t] += v;
        __syncthreads();
    }
    offs[t] = s[t] - my;    // exclusive prefix
}

__global__ __launch_bounds__(256) void k_sc_fill(
    const int* __restrict__ edst, const int* __restrict__ offs,
    const int* __restrict__ pos, int* __restrict__ slot) {
    int e = blockIdx.x * 256 + threadIdx.x;
    slot[offs[edst[e]] + pos[e]] = e;
}

__global__ __launch_bounds__(512) void k_sc_agg(
    const int* __restrict__ esrc, const int* __restrict__ etyp,
    const int* __restrict__ cnt, const int* __restrict__ offs,
    const int* __restrict__ slot, const float* __restrict__ m,
    float* __restrict__ agg) {
    int n = blockIdx.x, tid = threadIdx.x;
    __shared__ int sbase[128];
    int c0 = offs[n], c = cnt[n];
    float acc = 0.f;
    for (int i0 = 0; i0 < c; i0 += 128) {
        int chunk = min(128, c - i0);
        if (tid < chunk) {
            int e = slot[c0 + i0 + tid];
            sbase[tid] = (etyp[e] * N_ + esrc[e]) * D2_;
        }
        __syncthreads();
        for (int j = 0; j < chunk; j++)
            acc += m[(size_t)sbase[j] + tid];
        __syncthreads();
    }
    agg[(size_t)n * D2_ + tid] = acc;
}

// ------------------------------------- hs/ts = relu(ent@Wself + agg@Wmsg + b)
__global__ __launch_bounds__(256) void k_hsts(
    const float* __restrict__ ent, const float* __restrict__ agg,
    const float* __restrict__ wsh, const float* __restrict__ wmh, const float* __restrict__ bh,
    const float* __restrict__ wst, const float* __restrict__ wmt, const float* __restrict__ bt,
    float* __restrict__ hs, float* __restrict__ ts) {
    int n = blockIdx.x, ty = blockIdx.y;
    const float* Ws = ty ? wst : wsh;
    const float* Wm = ty ? wmt : wmh;
    const float* bi = ty ? bt : bh;
    float* out = ty ? ts : hs;
    __shared__ float se[512], sa[512];
    for (int idx = threadIdx.x; idx < 512; idx += 256) {
        se[idx] = ent[n * 512 + idx];
        sa[idx] = agg[n * 512 + idx];
    }
    __syncthreads();
    int d = threadIdx.x;
    float a0 = bi[d], a1 = bi[d + 256];
#pragma unroll 2
    for (int k = 0; k < 512; k++) {
        float e = se[k], a = sa[k];
        a0 += e * Ws[k * 512 + d] + a * Wm[k * 512 + d];
        a1 += e * Ws[k * 512 + d + 256] + a * Wm[k * 512 + d + 256];
    }
    out[n * 512 + d] = fmaxf(a0, 0.f);
    out[n * 512 + d + 256] = fmaxf(a1, 0.f);
}

// --------------------- pair gather + projections -> f16 hd/td (288-pad) + hp*tp
__global__ __launch_bounds__(256) void k_pairs(
    const float* __restrict__ hs, const float* __restrict__ ts,
    const int* __restrict__ hts, const int* __restrict__ dht, const int* __restrict__ dth,
    const float* __restrict__ hW, const float* __restrict__ hb,
    const float* __restrict__ tW, const float* __restrict__ tb,
    const float* __restrict__ dis,
    unsigned short* __restrict__ hdb, unsigned short* __restrict__ tdb,
    float* __restrict__ hptp) {
    int bp = blockIdx.x;                // b*P + p
    int b = bp >> 9;
    int hi = hts[bp * 2], ti = hts[bp * 2 + 1];
    __shared__ float sh[512], st[512];
    const float* hr = hs + ((size_t)(b * NE_ + hi)) * D2_;
    const float* tr = ts + ((size_t)(b * NE_ + ti)) * D2_;
    for (int idx = threadIdx.x; idx < 512; idx += 256) {
        sh[idx] = hr[idx];
        st[idx] = tr[idx];
    }
    __syncthreads();
    int d = threadIdx.x;
    float ah = hb[d], at = tb[d];
#pragma unroll 4
    for (int k = 0; k < 512; k++) {
        ah += sh[k] * hW[k * H_ + d];
        at += st[k] * tW[k * H_ + d];
    }
    size_t rb = (size_t)bp * 288;
    hdb[rb + d] = f16bits(ah);
    tdb[rb + d] = f16bits(at);
    hptp[(size_t)bp * H_ + d] = ah * at;
    if (d < DD_) {
        hdb[rb + 256 + d] = f16bits(dis[dht[bp] * DD_ + d]);
        tdb[rb + 256 + d] = f16bits(dis[dth[bp] * DD_ + d]);
    }
    if (d < 12) {
        hdb[rb + 276 + d] = 0;
        tdb[rb + 276 + d] = 0;
    }
}

// -------------------- bilinear as MFMA GEMM: blacc[p,k] += A(p,ij) Wb(ij,k)
__global__ __launch_bounds__(512) void k_bili(
    const unsigned short* __restrict__ Wb, const unsigned short* __restrict__ hdb,
    const unsigned short* __restrict__ tdb, float* __restrict__ blacc) {
    int bx = blockIdx.x, kc = blockIdx.y;
    int i0 = kc * 17 + (kc < 4 ? kc : 4);
    int cnt = 17 + (kc < 4 ? 1 : 0);
    int steps = cnt * 9;
    int tid = threadIdx.x;
    int w = tid >> 6, lane = tid & 63, q = lane >> 4, n16 = lane & 15;

    __shared__ alignas(16) unsigned short Bs[2][8192];
    __shared__ unsigned short hds[128 * 18];

    for (int e = tid; e < 128 * 18; e += 512)
        hds[e] = hdb[(size_t)(bx * 128 + e / 18) * 288 + i0 + e % 18];

    int p = bx * 128 + w * 16 + n16;
    const u4v* tdsrc = (const u4v*)(tdb + (size_t)p * 288);
    TDreg td[9];
#pragma unroll
    for (int jc = 0; jc < 9; jc++) td[jc].u = tdsrc[jc * 4 + q];

    f4v acc[16];
#pragma unroll
    for (int i = 0; i < 16; i++) acc[i] = (f4v)0.f;

    const u4v* gsrc = (const u4v*)Wb + (size_t)(i0 * 9) * 1024 + tid * 2;
    u4v r0 = gsrc[0], r1 = gsrc[1];
    {
        u4v* bs0 = (u4v*)(&Bs[0][0]);
        bs0[tid * 2] = r0; bs0[tid * 2 + 1] = r1;
    }
    __syncthreads();

    int il = 0, jc = 0;
    for (int s = 0; s < steps; s++) {
        if (s + 1 < steps) {
            const u4v* gs = gsrc + (size_t)(s + 1) * 1024;
            r0 = gs[0]; r1 = gs[1];
        }
        unsigned short hraw = hds[(w * 16 + n16) * 18 + il];
        _Float16 hv = __builtin_bit_cast(_Float16, hraw);
        h2v hd2 = {hv, hv};
        AFrag af;
#pragma unroll
        for (int e2 = 0; e2 < 4; e2++) af.h[e2] = hd2 * td[jc].h[e2];
        const unsigned short* bsc = &Bs[s & 1][0];
#pragma unroll
        for (int ns = 0; ns < 16; ns++) {
            h8v bf = *(const h8v*)(bsc + ns * 512 + lane * 8);
            acc[ns] = __builtin_amdgcn_mfma_f32_16x16x32_f16(af.v, bf, acc[ns], 0, 0, 0);
        }
        if (s + 1 < steps) {
            u4v* bsn = (u4v*)(&Bs[(s + 1) & 1][0]);
            bsn[tid * 2] = r0; bsn[tid * 2 + 1] = r1;
        }
        __syncthreads();
        if (++jc == 9) { jc = 0; il++; }
    }

    float* dst = blacc + (size_t)(bx * 128 + w * 16 + q * 4) * 256 + n16;
#pragma unroll
    for (int ns = 0; ns < 16; ns++)
#pragma unroll
        for (int r = 0; r < 4; r++)
            atomicAdd(dst + (size_t)r * 256 + ns * 16, acc[ns][r]);
}

// ------------------- logits = [relu(blacc + bili_b) | hp*tp] @ out_W + out_b
__global__ __launch_bounds__(128) void k_final(
    const float* __restrict__ blacc, const float* __restrict__ bib,
    const float* __restrict__ hptp,
    const float* __restrict__ oW, const float* __restrict__ ob,
    float* __restrict__ out) {
    int bp = blockIdx.x;
    __shared__ float s[512];
    for (int idx = threadIdx.x; idx < 512; idx += 128)
        s[idx] = (idx < 256) ? fmaxf(blacc[(size_t)bp * 256 + idx] + bib[idx], 0.f)
                             : hptp[(size_t)bp * 256 + idx - 256];
    __syncthreads();
    int r = threadIdx.x;
    if (r >= REL_) return;
    float a = ob[r];
#pragma unroll 4
    for (int d = 0; d < 512; d++) a += s[d] * oW[d * REL_ + r];
    out[(size_t)bp * REL_ + r] = a;
}

extern "C" void kernel_launch(void* const* d_in, const int* in_sizes, int n_in,
                              void* d_out, int out_size, void* d_ws, size_t ws_size,
                              hipStream_t stream) {
    const float* e_map    = (const float*)d_in[0];
    const float* word_t   = (const float*)d_in[1];
    const float* coref_t  = (const float*)d_in[2];
    const float* ner_t    = (const float*)d_in[3];
    const float* Wi_f     = (const float*)d_in[4];
    const float* Wh_f     = (const float*)d_in[5];
    const float* b_f      = (const float*)d_in[6];
    const float* Wi_b     = (const float*)d_in[7];
    const float* Wh_b     = (const float*)d_in[8];
    const float* b_b      = (const float*)d_in[9];
    const float* W_rel    = (const float*)d_in[10];
    const float* W_self_h = (const float*)d_in[11];
    const float* W_msg_h  = (const float*)d_in[12];
    const float* b_h      = (const float*)d_in[13];
    const float* W_self_t = (const float*)d_in[14];
    const float* W_msg_t  = (const float*)d_in[15];
    const float* b_t      = (const float*)d_in[16];
    const float* head_W   = (const float*)d_in[17];
    const float* head_b   = (const float*)d_in[18];
    const float* tail_W   = (const float*)d_in[19];
    const float* tail_b   = (const float*)d_in[20];
    const float* dis_t    = (const float*)d_in[21];
    const float* bili_W   = (const float*)d_in[22];
    const float* bili_b   = (const float*)d_in[23];
    const float* out_W    = (const float*)d_in[24];
    const float* out_b    = (const float*)d_in[25];
    const int* ctx_idx = (const int*)d_in[26];
    const int* pos     = (const int*)d_in[27];
    const int* ctx_ner = (const int*)d_in[28];
    const int* hts     = (const int*)d_in[29];
    const int* dht     = (const int*)d_in[30];
    const int* dth     = (const int*)d_in[31];
    const int* esrc    = (const int*)d_in[32];
    const int* edst    = (const int*)d_in[33];
    const int* etyp    = (const int*)d_in[34];

    float* ws = (float*)d_ws;
    float* emb  = ws + OFF_EMB;
    float* pre  = ws + OFF_PRE;
    float* docs = ws + OFF_DOCS;
    unsigned* whp = (unsigned*)(ws + OFF_WHP);
    float* ent  = ws + OFF_ENT;
    float* m    = ws + OFF_M;
    float* agg  = ws + OFF_AGG;
    float* hsb  = ws + OFF_HS;
    float* tsb  = ws + OFF_TS;
    float* hptp = ws + OFF_HPTP;
    float* blacc = ws + OFF_BL;
    unsigned short* Wb  = (unsigned short*)(ws + OFF_WB_F16);
    unsigned short* hdb = (unsigned short*)(ws + OFF_HDB_F16);
    unsigned short* tdb = (unsigned short*)(ws + OFF_TDB_F16);
    // scatter aux (ints) in the dead OFF_HD region
    int* aux   = (int*)(ws + OFF_HD);
    int* cnt_  = aux;                       // 256
    int* posb  = aux + 256;                 // E
    int* slot  = aux + 256 + E_;            // E
    int* offs  = aux + 256 + 2 * E_;        // 256
    float* out  = (float*)d_out;

    hipLaunchKernelGGL(k_embed, dim3(B_ * L_), dim3(192), 0, stream,
                       word_t, coref_t, ner_t, ctx_idx, pos, ctx_ner, emb);
    hipLaunchKernelGGL(k_pack_wh, dim3(1024), dim3(256), 0, stream, Wh_f, Wh_b, whp);
    hipLaunchKernelGGL(k_pregates, dim3(512, 2), dim3(256), 0, stream,
                       emb, Wi_f, b_f, Wi_b, b_b, pre);
    hipLaunchKernelGGL(k_lstm, dim3(8), dim3(512), 0, stream, pre, whp, docs);
    hipLaunchKernelGGL(k_pool, dim3(N_), dim3(256), 0, stream, e_map, docs, ent);
    // Wb overlays emb/pre/docs -> must come after k_pool
    hipLaunchKernelGGL(k_cvt_w, dim3(79488), dim3(256), 0, stream, bili_W, Wb);
    hipLaunchKernelGGL(k_msg, dim3(N_, R_), dim3(256), 0, stream, ent, W_rel, m);
    // bucketed segment-sum (replaces f32-atomic scatter)
    hipMemsetAsync(cnt_, 0, 256 * sizeof(int), stream);
    hipLaunchKernelGGL(k_sc_count, dim3(E_ / 256), dim3(256), 0, stream,
                       edst, cnt_, posb);
    hipLaunchKernelGGL(k_sc_scan, dim3(1), dim3(256), 0, stream, cnt_, offs);
    hipLaunchKernelGGL(k_sc_fill, dim3(E_ / 256), dim3(256), 0, stream,
                       edst, offs, posb, slot);
    hipLaunchKernelGGL(k_sc_agg, dim3(N_), dim3(512), 0, stream,
                       esrc, etyp, cnt_, offs, slot, m, agg);
    hipLaunchKernelGGL(k_hsts, dim3(N_, 2), dim3(256), 0, stream,
                       ent, agg, W_self_h, W_msg_h, b_h, W_self_t, W_msg_t, b_t, hsb, tsb);
    hipLaunchKernelGGL(k_pairs, dim3(B_ * P_), dim3(256), 0, stream,
                       hsb, tsb, hts, dht, dth, head_W, head_b, tail_W, tail_b,
                       dis_t, hdb, tdb, hptp);
    hipMemsetAsync(blacc, 0, (size_t)2048 * 256 * sizeof(float), stream);
    hipLaunchKernelGGL(k_bili, dim3(16, 16), dim3(512), 0, stream, Wb, hdb, tdb, blacc);
    hipLaunchKernelGGL(k_final, dim3(B_ * P_), dim3(128), 0, stream,
                       blacc, bili_b, hptp, out_W, out_b, out);
}

// Round 8
// 2189.334 us; speedup vs baseline: 2.1048x; 1.0085x over previous
//
#include <hip/hip_runtime.h>
#include <cstdint>

#define B_   4
#define L_   1024
#define H_   256
#define NE_  64
#define P_   512
#define E_   65536
#define R_   4
#define DW_  100
#define DC_  20
#define DT_  20
#define DD_  20
#define REL_ 97
#define N_   256      // B*NE
#define D2_  512
#define DBI_ 276
#define DIN_ 140
#define G4_  1024     // 4*H

// workspace offsets in floats
#define OFF_EMB  0u
#define OFF_PRE  573440u
#define OFF_DOCS 8962048u
#define OFF_WHP  11059200u
#define OFF_ENT  11321344u
#define OFF_M    11452416u
#define OFF_AGG  11976704u
#define OFF_HS   12107776u
#define OFF_TS   12238848u
#define OFF_HD   12369920u   // dead f32 region -> scatter aux (ints)
#define OFF_TD   12935168u
#define OFF_HPTP 13500416u
#define OFF_BL   14024704u
// f16 buffers overlaid on emb/pre/docs (dead after k_pool):
#define OFF_WB_F16   0u
#define OFF_HDB_F16  10174464u
#define OFF_TDB_F16  10469376u

typedef _Float16 h2v __attribute__((ext_vector_type(2)));
typedef _Float16 h8v __attribute__((ext_vector_type(8)));
typedef float f4v __attribute__((ext_vector_type(4)));
typedef unsigned int u4v __attribute__((ext_vector_type(4)));

union AFrag { h8v v; h2v h[4]; };
union TDreg { u4v u; h2v h[4]; };

__device__ __forceinline__ unsigned short f16bits(float x) {
    return __builtin_bit_cast(unsigned short, (_Float16)x);
}

// fast hw transcendentals: v_exp_f32 computes 2^x, v_rcp_f32 ~1ulp.
#if __has_builtin(__builtin_amdgcn_exp2f)
#define EXP2F __builtin_amdgcn_exp2f
#else
#define EXP2F exp2f
#endif
#if __has_builtin(__builtin_amdgcn_rcpf)
#define RCPF __builtin_amdgcn_rcpf
#else
#define RCPF(x) (1.0f / (x))
#endif

__device__ __forceinline__ float fast_sig(float x) {
    return RCPF(1.0f + EXP2F(x * -1.44269504f));
}
__device__ __forceinline__ float fast_tanh(float x) {
    return 1.0f - 2.0f * RCPF(EXP2F(x * 2.88539008f) + 1.0f);
}

__device__ __forceinline__ f4v MF(h8v a, u4v b, f4v c) {
    return __builtin_amdgcn_mfma_f32_16x16x32_f16(
        a, __builtin_bit_cast(h8v, b), c, 0, 0, 0);
}

// ------------------- merged: embeddings (bid<4096) + Wh pack (bid>=4096)
// pack: whp u32 index = (((dir*64 + n)*8 + kk)*64 + lane)*4 + m
//   value pack(f16(Wh[k0][col]), f16(Wh[k0+1][col]));
//   k0 = kk*32 + (lane>>4)*8 + 2m, col = n*16 + (lane&15)
// = per-lane B operand of v_mfma_f32_16x16x32_f16 for tile n, K-tile kk.
__global__ __launch_bounds__(256) void k_prep(
    const float* __restrict__ wt, const float* __restrict__ ct,
    const float* __restrict__ nt, const int* __restrict__ widx,
    const int* __restrict__ pidx, const int* __restrict__ nidx,
    float* __restrict__ emb,
    const float* __restrict__ whf, const float* __restrict__ whb,
    unsigned* __restrict__ whp) {
    int bid = blockIdx.x;
    if (bid < 4096) {                   // ---- embed: row = b*L + l
        int row = bid, t = threadIdx.x;
        if (t >= DIN_) return;
        float v;
        if (t < DW_)            v = wt[(size_t)widx[row] * DW_ + t];
        else if (t < DW_ + DC_) v = ct[pidx[row] * DC_ + (t - DW_)];
        else                    v = nt[nidx[row] * DT_ + (t - DW_ - DC_)];
        emb[(size_t)row * DIN_ + t] = v;
    } else {                            // ---- pack Wh
        unsigned gid = (unsigned)(bid - 4096) * 256u + threadIdx.x; // 2^18
        unsigned m    = gid & 3u;
        unsigned lane = (gid >> 2) & 63u;
        unsigned kk   = (gid >> 8) & 7u;
        unsigned n    = (gid >> 11) & 63u;
        unsigned dir  = gid >> 17;
        const float* src = dir ? whb : whf;
        unsigned k0  = kk * 32u + (lane >> 4) * 8u + 2u * m;
        unsigned col = n * 16u + (lane & 15u);
        unsigned lo = f16bits(src[(size_t)k0 * G4_ + col]);
        unsigned hi = f16bits(src[(size_t)(k0 + 1) * G4_ + col]);
        whp[gid] = (hi << 16) | lo;
    }
}

// ------------------- pre-gates: emb @ Wi + b (both dirs), 16 rows/block
// (halves Wi L2 re-reads vs 8-row version: 293 MB instead of 587 MB)
__global__ __launch_bounds__(256) void k_pregates(
    const float* __restrict__ emb,
    const float* __restrict__ wif, const float* __restrict__ bf,
    const float* __restrict__ wib, const float* __restrict__ bb,
    float* __restrict__ pre) {
    int dir = blockIdx.y;
    const float* Wi   = dir ? wib : wif;
    const float* bias = dir ? bb : bf;
    int x16 = blockIdx.x * 16;          // 16 (b,l) rows per block
    __shared__ float se[16 * DIN_];
    for (int idx = threadIdx.x; idx < 16 * DIN_; idx += 256)
        se[idx] = emb[(size_t)(x16 + idx / DIN_) * DIN_ + idx % DIN_];
    __syncthreads();
    int t = threadIdx.x;
    float acc[16][4];
#pragma unroll
    for (int r = 0; r < 16; r++)
#pragma unroll
        for (int q = 0; q < 4; q++) acc[r][q] = bias[t + q * 256];
    for (int k = 0; k < DIN_; k++) {
        float w0 = Wi[k * G4_ + t];
        float w1 = Wi[k * G4_ + t + 256];
        float w2 = Wi[k * G4_ + t + 512];
        float w3 = Wi[k * G4_ + t + 768];
#pragma unroll
        for (int r = 0; r < 16; r++) {
            float e = se[r * DIN_ + k];
            acc[r][0] += e * w0; acc[r][1] += e * w1;
            acc[r][2] += e * w2; acc[r][3] += e * w3;
        }
    }
#pragma unroll
    for (int r = 0; r < 16; r++) {
        float* dst = pre + ((size_t)(dir * 4096 + x16 + r)) * G4_ + t;
        dst[0] = acc[r][0]; dst[256] = acc[r][1];
        dst[512] = acc[r][2]; dst[768] = acc[r][3];
    }
}

// --------------- BiLSTM v6 (frozen): full-K waves, one barrier per step.
// 8 blocks (dir x batch) x 512 threads = 8 waves, 2 waves/SIMD. Wave w owns
// unit-groups 2w, 2w+1; i/f/g weights in regs (48 u4v, AGPR-backed; arch 128
// + accum 128 = the exact 256/wave cap -> NO headroom for staging regs),
// o-gate tiles stream from LDS (128 KiB = the structural DS floor).
__global__ __launch_bounds__(512)
__attribute__((amdgpu_waves_per_eu(2)))
void k_lstm(
    const float* __restrict__ pre, const unsigned* __restrict__ whb,
    float* __restrict__ docs) {
    int dir = blockIdx.x >> 2, b = blockIdx.x & 3;
    int tid = threadIdx.x;
    int w = tid >> 6;
    int lane = tid & 63, q = lane >> 4, c = lane & 15;
    __shared__ alignas(16) u4v wl[16][8][64];       // 128 KiB o-gate tiles
    __shared__ alignas(16) unsigned hbuf[2][128];   // h f16 pairs, dbuf
    const float* pb = pre + (size_t)(dir * 4 + b) * (1024 * 1024);
    const u4v* wsrc = (const u4v*)whb + (size_t)dir * 32768;

    u4v wr[2][3][8];
#pragma unroll
    for (int j2 = 0; j2 < 2; j2++)
#pragma unroll
        for (int gt = 0; gt < 3; gt++)
#pragma unroll
            for (int kk = 0; kk < 8; kk++)
                wr[j2][gt][kk] =
                    wsrc[(size_t)((2 * w + j2 + 16 * gt) * 8 + kk) * 64 + lane];
#pragma unroll
    for (int j2 = 0; j2 < 2; j2++)
#pragma unroll
        for (int kk = 0; kk < 8; kk++)
            wl[2 * w + j2][kk][lane] =
                wsrc[(size_t)((2 * w + j2 + 48) * 8 + kk) * 64 + lane];
    if (tid < 256) ((unsigned*)hbuf)[tid] = 0;

    bool is_act = (q < 2);
    int j2a = q & 1;
    int u_act = 32 * w + 16 * j2a + c;
    float cst = 0.f;
    __syncthreads();

#pragma unroll 1
    for (int t = 0; t < L_; ++t) {
        int row = dir ? (L_ - 1 - t) : t;
        int cur = t & 1;
        float pr0, pr1, pr2, pr3;
        if (is_act) {
            const float* prow = pb + (size_t)row * 1024 + u_act;
            pr0 = prow[0]; pr1 = prow[256]; pr2 = prow[512]; pr3 = prow[768];
        }
        const u4v* hb4 = (const u4v*)&hbuf[cur][0];
        f4v a00 = (f4v)0.f, a01 = (f4v)0.f, a02 = (f4v)0.f, a03 = (f4v)0.f;
        f4v a10 = (f4v)0.f, a11 = (f4v)0.f, a12 = (f4v)0.f, a13 = (f4v)0.f;
#pragma unroll
        for (int kk = 0; kk < 8; kk++) {
            h8v a = __builtin_bit_cast(h8v, hb4[kk * 4 + q]);   // broadcast h
            u4v l0 = wl[2 * w][kk][lane];
            u4v l1 = wl[2 * w + 1][kk][lane];
            a00 = MF(a, wr[0][0][kk], a00);
            a01 = MF(a, wr[0][1][kk], a01);
            a02 = MF(a, wr[0][2][kk], a02);
            a03 = MF(a, l0, a03);
            a10 = MF(a, wr[1][0][kk], a10);
            a11 = MF(a, wr[1][1][kk], a11);
            a12 = MF(a, wr[1][2][kk], a12);
            a13 = MF(a, l1, a13);
        }
        if (is_act) {
            float ig = (j2a ? a10.x : a00.x) + pr0;
            float fg = (j2a ? a11.x : a01.x) + pr1;
            float gg = (j2a ? a12.x : a02.x) + pr2;
            float og = (j2a ? a13.x : a03.x) + pr3;
            float si = fast_sig(ig), sf = fast_sig(fg), so = fast_sig(og);
            cst = sf * cst + si * fast_tanh(gg);
            float h = so * fast_tanh(cst);
            ((_Float16*)hbuf)[(cur ^ 1) * 256 + u_act] = (_Float16)h;
            docs[((size_t)(b * L_ + row)) * D2_ + dir * H_ + u_act] = h;
        }
        __syncthreads();
    }
}

// -------------------------------------------------- entity pooling e_map @ docs
__global__ __launch_bounds__(256) void k_pool(
    const float* __restrict__ emap, const float* __restrict__ docs,
    float* __restrict__ ent) {
    int n = blockIdx.x;                 // b*64 + e
    int b = n >> 6;
    __shared__ float sm[1024];
    for (int idx = threadIdx.x; idx < 1024; idx += 256)
        sm[idx] = emap[(size_t)n * 1024 + idx];
    __syncthreads();
    int d = threadIdx.x;
    float a0 = 0.f, a1 = 0.f;
    const float* db = docs + (size_t)b * L_ * D2_;
#pragma unroll 4
    for (int l = 0; l < L_; l++) {
        float mv = sm[l];
        a0 += mv * db[l * D2_ + d];
        a1 += mv * db[l * D2_ + d + 256];
    }
    ent[n * D2_ + d] = a0;
    ent[n * D2_ + d + 256] = a1;
}

// ------------- merged: per-relation messages (bid<1024) + bili_W cvt (rest)
// msg: relu(ent @ W_rel[r]) ; cvt: fp32 [276][276][256] -> swizzled padded f16
__global__ __launch_bounds__(256) void k_cvt_msg(
    const float* __restrict__ W, unsigned short* __restrict__ Wb,
    const float* __restrict__ ent, const float* __restrict__ wrel,
    float* __restrict__ m) {
    int bid = blockIdx.x;
    __shared__ float se[512];
    if (bid < 1024) {                   // ---- msg
        int n = bid & 255, r = bid >> 8;
        for (int idx = threadIdx.x; idx < 512; idx += 256)
            se[idx] = ent[n * D2_ + idx];
        __syncthreads();
        int d = threadIdx.x;
        const float* Wr = wrel + (size_t)r * D2_ * D2_;
        float a0 = 0.f, a1 = 0.f;
#pragma unroll 4
        for (int k = 0; k < 512; k++) {
            float e = se[k];
            a0 += e * Wr[k * 512 + d];
            a1 += e * Wr[k * 512 + d + 256];
        }
        size_t o = ((size_t)(r * N_ + n)) * D2_;
        m[o + d] = fmaxf(a0, 0.f);
        m[o + d + 256] = fmaxf(a1, 0.f);
    } else {                            // ---- cvt_w
        unsigned gid = (unsigned)(bid - 1024) * 256u + threadIdx.x;
        unsigned t = gid & 7u;
        unsigned np = (gid >> 3) & 15u;
        unsigned q = (gid >> 7) & 3u;
        unsigned ns = (gid >> 9) & 15u;
        unsigned c = gid >> 13;
        unsigned i = c / 9u, jc = c - i * 9u;
        unsigned jp = jc * 32u + q * 8u + t;
        float v = (jp < 276u) ? W[((size_t)i * 276u + jp) * 256u + ns * 16u + np] : 0.f;
        Wb[gid] = f16bits(v);
    }
}

// ---------------- scatter bucketing (no f32 atomics). aux ints in OFF_HD:
//   cnt[256] | pos[E] | slot[E] | offs[256]
__global__ __launch_bounds__(256) void k_sc_count(
    const int* __restrict__ edst, int* __restrict__ cnt, int* __restrict__ pos) {
    int e = blockIdx.x * 256 + threadIdx.x;
    pos[e] = atomicAdd(&cnt[edst[e]], 1);
}

__global__ __launch_bounds__(256) void k_sc_scan(
    const int* __restrict__ cnt, int* __restrict__ offs) {
    __shared__ int s[256];
    int t = threadIdx.x;
    int my = cnt[t];
    s[t] = my;
    __syncthreads();
    for (int d = 1; d < 256; d <<= 1) {
        int v = (t >= d) ? s[t - d] : 0;
        __syncthreads();
        s[t] += v;
        __syncthreads();
    }
    offs[t] = s[t] - my;    // exclusive prefix
}

__global__ __launch_bounds__(256) void k_sc_fill(
    const int* __restrict__ edst, const int* __restrict__ offs,
    const int* __restrict__ pos, int* __restrict__ slot) {
    int e = blockIdx.x * 256 + threadIdx.x;
    slot[offs[edst[e]] + pos[e]] = e;
}

// ------------- fused: dense segment-sum (agg) + hs/ts GEMV. agg never leaves
// the block: phase-1 reduces edges into sa[] (LDS), phase-2 does
// relu(ent@Wself + agg@Wmsg + b) with ty = tid>>8, d = tid&255.
__global__ __launch_bounds__(512) void k_agg_hsts(
    const int* __restrict__ esrc, const int* __restrict__ etyp,
    const int* __restrict__ cnt, const int* __restrict__ offs,
    const int* __restrict__ slot, const float* __restrict__ m,
    const float* __restrict__ ent,
    const float* __restrict__ wsh, const float* __restrict__ wmh, const float* __restrict__ bh,
    const float* __restrict__ wst, const float* __restrict__ wmt, const float* __restrict__ bt,
    float* __restrict__ hs, float* __restrict__ ts) {
    int n = blockIdx.x, tid = threadIdx.x;
    __shared__ int sbase[128];
    __shared__ float sa[512], se[512];
    int c0 = offs[n], c = cnt[n];
    float acc = 0.f;
    for (int i0 = 0; i0 < c; i0 += 128) {
        int chunk = min(128, c - i0);
        if (tid < chunk) {
            int e = slot[c0 + i0 + tid];
            sbase[tid] = (etyp[e] * N_ + esrc[e]) * D2_;
        }
        __syncthreads();
        for (int j = 0; j < chunk; j++)
            acc += m[(size_t)sbase[j] + tid];
        __syncthreads();
    }
    sa[tid] = acc;
    se[tid] = ent[n * 512 + tid];
    __syncthreads();
    int ty = tid >> 8, d = tid & 255;
    const float* Ws = ty ? wst : wsh;
    const float* Wm = ty ? wmt : wmh;
    const float* bi = ty ? bt : bh;
    float* out = ty ? ts : hs;
    float a0 = bi[d], a1 = bi[d + 256];
#pragma unroll 2
    for (int k = 0; k < 512; k++) {
        float e = se[k], a = sa[k];
        a0 += e * Ws[k * 512 + d] + a * Wm[k * 512 + d];
        a1 += e * Ws[k * 512 + d + 256] + a * Wm[k * 512 + d + 256];
    }
    out[n * 512 + d] = fmaxf(a0, 0.f);
    out[n * 512 + d + 256] = fmaxf(a1, 0.f);
}

// --------------------- pair gather + projections -> f16 hd/td (288-pad) + hp*tp
__global__ __launch_bounds__(256) void k_pairs(
    const float* __restrict__ hs, const float* __restrict__ ts,
    const int* __restrict__ hts, const int* __restrict__ dht, const int* __restrict__ dth,
    const float* __restrict__ hW, const float* __restrict__ hb,
    const float* __restrict__ tW, const float* __restrict__ tb,
    const float* __restrict__ dis,
    unsigned short* __restrict__ hdb, unsigned short* __restrict__ tdb,
    float* __restrict__ hptp) {
    int bp = blockIdx.x;                // b*P + p
    int b = bp >> 9;
    int hi = hts[bp * 2], ti = hts[bp * 2 + 1];
    __shared__ float sh[512], st[512];
    const float* hr = hs + ((size_t)(b * NE_ + hi)) * D2_;
    const float* tr = ts + ((size_t)(b * NE_ + ti)) * D2_;
    for (int idx = threadIdx.x; idx < 512; idx += 256) {
        sh[idx] = hr[idx];
        st[idx] = tr[idx];
    }
    __syncthreads();
    int d = threadIdx.x;
    float ah = hb[d], at = tb[d];
#pragma unroll 4
    for (int k = 0; k < 512; k++) {
        ah += sh[k] * hW[k * H_ + d];
        at += st[k] * tW[k * H_ + d];
    }
    size_t rb = (size_t)bp * 288;
    hdb[rb + d] = f16bits(ah);
    tdb[rb + d] = f16bits(at);
    hptp[(size_t)bp * H_ + d] = ah * at;
    if (d < DD_) {
        hdb[rb + 256 + d] = f16bits(dis[dht[bp] * DD_ + d]);
        tdb[rb + 256 + d] = f16bits(dis[dth[bp] * DD_ + d]);
    }
    if (d < 12) {
        hdb[rb + 276 + d] = 0;
        tdb[rb + 276 + d] = 0;
    }
}

// -------------------- bilinear as MFMA GEMM: blacc[p,k] += A(p,ij) Wb(ij,k)
__global__ __launch_bounds__(512) void k_bili(
    const unsigned short* __restrict__ Wb, const unsigned short* __restrict__ hdb,
    const unsigned short* __restrict__ tdb, float* __restrict__ blacc) {
    int bx = blockIdx.x, kc = blockIdx.y;
    int i0 = kc * 17 + (kc < 4 ? kc : 4);
    int cnt = 17 + (kc < 4 ? 1 : 0);
    int steps = cnt * 9;
    int tid = threadIdx.x;
    int w = tid >> 6, lane = tid & 63, q = lane >> 4, n16 = lane & 15;

    __shared__ alignas(16) unsigned short Bs[2][8192];
    __shared__ unsigned short hds[128 * 18];

    for (int e = tid; e < 128 * 18; e += 512)
        hds[e] = hdb[(size_t)(bx * 128 + e / 18) * 288 + i0 + e % 18];

    int p = bx * 128 + w * 16 + n16;
    const u4v* tdsrc = (const u4v*)(tdb + (size_t)p * 288);
    TDreg td[9];
#pragma unroll
    for (int jc = 0; jc < 9; jc++) td[jc].u = tdsrc[jc * 4 + q];

    f4v acc[16];
#pragma unroll
    for (int i = 0; i < 16; i++) acc[i] = (f4v)0.f;

    const u4v* gsrc = (const u4v*)Wb + (size_t)(i0 * 9) * 1024 + tid * 2;
    u4v r0 = gsrc[0], r1 = gsrc[1];
    {
        u4v* bs0 = (u4v*)(&Bs[0][0]);
        bs0[tid * 2] = r0; bs0[tid * 2 + 1] = r1;
    }
    __syncthreads();

    int il = 0, jc = 0;
    for (int s = 0; s < steps; s++) {
        if (s + 1 < steps) {
            const u4v* gs = gsrc + (size_t)(s + 1) * 1024;
            r0 = gs[0]; r1 = gs[1];
        }
        unsigned short hraw = hds[(w * 16 + n16) * 18 + il];
        _Float16 hv = __builtin_bit_cast(_Float16, hraw);
        h2v hd2 = {hv, hv};
        AFrag af;
#pragma unroll
        for (int e2 = 0; e2 < 4; e2++) af.h[e2] = hd2 * td[jc].h[e2];
        const unsigned short* bsc = &Bs[s & 1][0];
#pragma unroll
        for (int ns = 0; ns < 16; ns++) {
            h8v bf = *(const h8v*)(bsc + ns * 512 + lane * 8);
            acc[ns] = __builtin_amdgcn_mfma_f32_16x16x32_f16(af.v, bf, acc[ns], 0, 0, 0);
        }
        if (s + 1 < steps) {
            u4v* bsn = (u4v*)(&Bs[(s + 1) & 1][0]);
            bsn[tid * 2] = r0; bsn[tid * 2 + 1] = r1;
        }
        __syncthreads();
        if (++jc == 9) { jc = 0; il++; }
    }

    float* dst = blacc + (size_t)(bx * 128 + w * 16 + q * 4) * 256 + n16;
#pragma unroll
    for (int ns = 0; ns < 16; ns++)
#pragma unroll
        for (int r = 0; r < 4; r++)
            atomicAdd(dst + (size_t)r * 256 + ns * 16, acc[ns][r]);
}

// ------------------- logits = [relu(blacc + bili_b) | hp*tp] @ out_W + out_b
__global__ __launch_bounds__(128) void k_final(
    const float* __restrict__ blacc, const float* __restrict__ bib,
    const float* __restrict__ hptp,
    const float* __restrict__ oW, const float* __restrict__ ob,
    float* __restrict__ out) {
    int bp = blockIdx.x;
    __shared__ float s[512];
    for (int idx = threadIdx.x; idx < 512; idx += 128)
        s[idx] = (idx < 256) ? fmaxf(blacc[(size_t)bp * 256 + idx] + bib[idx], 0.f)
                             : hptp[(size_t)bp * 256 + idx - 256];
    __syncthreads();
    int r = threadIdx.x;
    if (r >= REL_) return;
    float a = ob[r];
#pragma unroll 4
    for (int d = 0; d < 512; d++) a += s[d] * oW[d * REL_ + r];
    out[(size_t)bp * REL_ + r] = a;
}

extern "C" void kernel_launch(void* const* d_in, const int* in_sizes, int n_in,
                              void* d_out, int out_size, void* d_ws, size_t ws_size,
                              hipStream_t stream) {
    const float* e_map    = (const float*)d_in[0];
    const float* word_t   = (const float*)d_in[1];
    const float* coref_t  = (const float*)d_in[2];
    const float* ner_t    = (const float*)d_in[3];
    const float* Wi_f     = (const float*)d_in[4];
    const float* Wh_f     = (const float*)d_in[5];
    const float* b_f      = (const float*)d_in[6];
    const float* Wi_b     = (const float*)d_in[7];
    const float* Wh_b     = (const float*)d_in[8];
    const float* b_b      = (const float*)d_in[9];
    const float* W_rel    = (const float*)d_in[10];
    const float* W_self_h = (const float*)d_in[11];
    const float* W_msg_h  = (const float*)d_in[12];
    const float* b_h      = (const float*)d_in[13];
    const float* W_self_t = (const float*)d_in[14];
    const float* W_msg_t  = (const float*)d_in[15];
    const float* b_t      = (const float*)d_in[16];
    const float* head_W   = (const float*)d_in[17];
    const float* head_b   = (const float*)d_in[18];
    const float* tail_W   = (const float*)d_in[19];
    const float* tail_b   = (const float*)d_in[20];
    const float* dis_t    = (const float*)d_in[21];
    const float* bili_W   = (const float*)d_in[22];
    const float* bili_b   = (const float*)d_in[23];
    const float* out_W    = (const float*)d_in[24];
    const float* out_b    = (const float*)d_in[25];
    const int* ctx_idx = (const int*)d_in[26];
    const int* pos     = (const int*)d_in[27];
    const int* ctx_ner = (const int*)d_in[28];
    const int* hts     = (const int*)d_in[29];
    const int* dht     = (const int*)d_in[30];
    const int* dth     = (const int*)d_in[31];
    const int* esrc    = (const int*)d_in[32];
    const int* edst    = (const int*)d_in[33];
    const int* etyp    = (const int*)d_in[34];

    float* ws = (float*)d_ws;
    float* emb  = ws + OFF_EMB;
    float* pre  = ws + OFF_PRE;
    float* docs = ws + OFF_DOCS;
    unsigned* whp = (unsigned*)(ws + OFF_WHP);
    float* ent  = ws + OFF_ENT;
    float* m    = ws + OFF_M;
    float* hsb  = ws + OFF_HS;
    float* tsb  = ws + OFF_TS;
    float* hptp = ws + OFF_HPTP;
    float* blacc = ws + OFF_BL;
    unsigned short* Wb  = (unsigned short*)(ws + OFF_WB_F16);
    unsigned short* hdb = (unsigned short*)(ws + OFF_HDB_F16);
    unsigned short* tdb = (unsigned short*)(ws + OFF_TDB_F16);
    // scatter aux (ints) in the dead OFF_HD region
    int* aux   = (int*)(ws + OFF_HD);
    int* cnt_  = aux;                       // 256
    int* posb  = aux + 256;                 // E
    int* slot  = aux + 256 + E_;            // E
    int* offs  = aux + 256 + 2 * E_;        // 256
    float* out  = (float*)d_out;

    hipLaunchKernelGGL(k_prep, dim3(4096 + 1024), dim3(256), 0, stream,
                       word_t, coref_t, ner_t, ctx_idx, pos, ctx_ner, emb,
                       Wh_f, Wh_b, whp);
    hipLaunchKernelGGL(k_pregates, dim3(256, 2), dim3(256), 0, stream,
                       emb, Wi_f, b_f, Wi_b, b_b, pre);
    hipLaunchKernelGGL(k_lstm, dim3(8), dim3(512), 0, stream, pre, whp, docs);
    hipLaunchKernelGGL(k_pool, dim3(N_), dim3(256), 0, stream, e_map, docs, ent);
    // Wb overlays emb/pre/docs -> cvt must come after k_pool (merged w/ msg)
    hipLaunchKernelGGL(k_cvt_msg, dim3(1024 + 79488), dim3(256), 0, stream,
                       bili_W, Wb, ent, W_rel, m);
    // bucketed segment-sum prep (no f32 atomics)
    hipMemsetAsync(cnt_, 0, 256 * sizeof(int), stream);
    hipLaunchKernelGGL(k_sc_count, dim3(E_ / 256), dim3(256), 0, stream,
                       edst, cnt_, posb);
    hipLaunchKernelGGL(k_sc_scan, dim3(1), dim3(256), 0, stream, cnt_, offs);
    hipLaunchKernelGGL(k_sc_fill, dim3(E_ / 256), dim3(256), 0, stream,
                       edst, offs, posb, slot);
    hipLaunchKernelGGL(k_agg_hsts, dim3(N_), dim3(512), 0, stream,
                       esrc, etyp, cnt_, offs, slot, m, ent,
                       W_self_h, W_msg_h, b_h, W_self_t, W_msg_t, b_t, hsb, tsb);
    hipLaunchKernelGGL(k_pairs, dim3(B_ * P_), dim3(256), 0, stream,
                       hsb, tsb, hts, dht, dth, head_W, head_b, tail_W, tail_b,
                       dis_t, hdb, tdb, hptp);
    hipMemsetAsync(blacc, 0, (size_t)2048 * 256 * sizeof(float), stream);
    hipLaunchKernelGGL(k_bili, dim3(16, 16), dim3(512), 0, stream, Wb, hdb, tdb, blacc);
    hipLaunchKernelGGL(k_final, dim3(B_ * P_), dim3(128), 0, stream,
                       blacc, bili_b, hptp, out_W, out_b, out);
}